// Round 1
// baseline (2228.303 us; speedup 1.0000x reference)
//
#include <hip/hip_runtime.h>

#define NN 262144
#define CC 4096

__device__ __forceinline__ unsigned short f_to_bf16u(float f) {
  union { float f; unsigned u; } v; v.f = f;
  unsigned u = v.u;
  u += 0x7fffu + ((u >> 16) & 1u);           // round-to-nearest-even
  return (unsigned short)(u >> 16);
}

// ---------- kernel A: enc MLP (3->32->64), segment-max via atomicMax ----------
__global__ __launch_bounds__(256) void k_enc(
    const float* __restrict__ pts, const int* __restrict__ cluster,
    const float* __restrict__ eW1, const float* __restrict__ eb1,
    const float* __restrict__ eW2, const float* __restrict__ eb2,
    float* __restrict__ neigh)
{
  __shared__ float h1s[256 * 33];            // stride 33 words -> conflict-free
  const int t = threadIdx.x;
  const int i = blockIdx.x * 256 + t;
  const float p0 = pts[i * 3 + 0], p1 = pts[i * 3 + 1], p2 = pts[i * 3 + 2];
  float* hrow = h1s + t * 33;
#pragma unroll
  for (int c = 0; c < 32; ++c) {
    float a = fmaf(p2, eW1[64 + c], fmaf(p1, eW1[32 + c], fmaf(p0, eW1[c], eb1[c])));
    hrow[c] = fmaxf(a, 0.f);
  }
  float h2[64];
#pragma unroll
  for (int c = 0; c < 64; ++c) h2[c] = eb2[c];
#pragma unroll 4
  for (int k = 0; k < 32; ++k) {
    const float hk = hrow[k];
    const float* __restrict__ w = eW2 + k * 64;
#pragma unroll
    for (int c = 0; c < 64; ++c) h2[c] = fmaf(hk, w[c], h2[c]);
  }
  const int cid = cluster[i];
  int* dst = (int*)(neigh + (size_t)cid * 64);
#pragma unroll
  for (int c = 0; c < 64; ++c) atomicMax(dst + c, __float_as_int(h2[c]));
}

// ---------- kernel A2: cproj[C,128] = neigh @ W1[67:131] + b1 ----------
__global__ __launch_bounds__(256) void k_cproj(
    const float* __restrict__ neigh, const float* __restrict__ W1,
    const float* __restrict__ b1, float* __restrict__ cproj)
{
  const int c = threadIdx.x & 127;
  const int r = blockIdx.x * 2 + (threadIdx.x >> 7);
  const float* __restrict__ Wd = W1 + 67 * 128;
  const float* __restrict__ nr = neigh + r * 64;   // wave-uniform row
  float acc = b1[c];
#pragma unroll 8
  for (int k = 0; k < 64; ++k) acc = fmaf(nr[k], Wd[k * 128 + c], acc);
  cproj[r * 128 + c] = acc;
}

// ---------- kernel B: fc1(feat,pts,cproj-gather) + fc2, segment-max ----------
__global__ __launch_bounds__(256) void k_main(
    const float* __restrict__ pts, const float* __restrict__ feat,
    const int* __restrict__ cluster,
    const float* __restrict__ W1, const float* __restrict__ W2,
    const float* __restrict__ b2, const float* __restrict__ cproj,
    float* __restrict__ gmax)
{
  __shared__ unsigned e1s[256 * 65];         // per-thread row, stride 65 u32 (pad)
  const int t = threadIdx.x;
  const int i = blockIdx.x * 256 + t;
  const float p0 = pts[i * 3 + 0], p1 = pts[i * 3 + 1], p2 = pts[i * 3 + 2];
  const int cid = cluster[i];
  const float* __restrict__ cp = cproj + (size_t)cid * 128;
  const float4* __restrict__ fr = reinterpret_cast<const float4*>(feat + (size_t)i * 64);
  const float* __restrict__ Wp = W1;          // rows 0..2  (points part)
  const float* __restrict__ Wf = W1 + 3 * 128; // rows 3..66 (features part)
  unsigned* __restrict__ rowu = e1s + t * 65;

  // ---- fc1: acc[128] = cp(=dup@Wd+b1) + pts@Wp + feat@Wf ----
  float acc[128];
#pragma unroll
  for (int c = 0; c < 128; ++c) acc[c] = cp[c];
#pragma unroll
  for (int c = 0; c < 128; ++c)
    acc[c] = fmaf(p2, Wp[256 + c], fmaf(p1, Wp[128 + c], fmaf(p0, Wp[c], acc[c])));
#pragma unroll 2
  for (int k4 = 0; k4 < 16; ++k4) {
    const float4 fv = fr[k4];
    const float* __restrict__ w0 = Wf + (4 * k4 + 0) * 128;
    const float* __restrict__ w1 = Wf + (4 * k4 + 1) * 128;
    const float* __restrict__ w2 = Wf + (4 * k4 + 2) * 128;
    const float* __restrict__ w3 = Wf + (4 * k4 + 3) * 128;
#pragma unroll
    for (int c = 0; c < 128; ++c) {
      acc[c] = fmaf(fv.x, w0[c], acc[c]);
      acc[c] = fmaf(fv.y, w1[c], acc[c]);
      acc[c] = fmaf(fv.z, w2[c], acc[c]);
      acc[c] = fmaf(fv.w, w3[c], acc[c]);
    }
  }
  // relu + pack bf16 pairs into own LDS row (no barrier needed: private row)
#pragma unroll
  for (int c = 0; c < 64; ++c) {
    const float a0 = fmaxf(acc[2 * c + 0], 0.f);
    const float a1 = fmaxf(acc[2 * c + 1], 0.f);
    rowu[c] = (unsigned)f_to_bf16u(a0) | ((unsigned)f_to_bf16u(a1) << 16);
  }

  // ---- fc2: 4 col-chunks of 32, k rolled over LDS-staged e1 ----
  int* gm = (int*)(gmax + (size_t)cid * 128);
#pragma unroll
  for (int ch = 0; ch < 4; ++ch) {
    const int cb = ch * 32;
    float a2[32];
#pragma unroll
    for (int c = 0; c < 32; ++c) a2[c] = b2[cb + c];
#pragma unroll 2
    for (int kk = 0; kk < 64; ++kk) {
      const unsigned u = rowu[kk];
      const float e0 = __uint_as_float(u << 16);
      const float e1 = __uint_as_float(u & 0xffff0000u);
      const float* __restrict__ w0 = W2 + (2 * kk + 0) * 128 + cb;
      const float* __restrict__ w1 = W2 + (2 * kk + 1) * 128 + cb;
#pragma unroll
      for (int c = 0; c < 32; ++c) {
        a2[c] = fmaf(e0, w0[c], a2[c]);
        a2[c] = fmaf(e1, w1[c], a2[c]);
      }
    }
#pragma unroll
    for (int c = 0; c < 32; ++c) atomicMax(gm + cb + c, __float_as_int(a2[c]));
  }
}

// ---------- kernel C1: tmpg[C,128] = relu(gmax @ G1 + gb1) ----------
__global__ __launch_bounds__(128) void k_g1(
    const float* __restrict__ gmax, const float* __restrict__ G1,
    const float* __restrict__ gb1, float* __restrict__ tmpg)
{
  const int c = threadIdx.x;                 // 0..127
  const int r0 = blockIdx.x * 4;
  const float* __restrict__ x0 = gmax + (size_t)(r0 + 0) * 128;
  const float* __restrict__ x1 = gmax + (size_t)(r0 + 1) * 128;
  const float* __restrict__ x2 = gmax + (size_t)(r0 + 2) * 128;
  const float* __restrict__ x3 = gmax + (size_t)(r0 + 3) * 128;
  float a0 = gb1[c], a1 = a0, a2 = a0, a3 = a0;
#pragma unroll 4
  for (int k = 0; k < 128; ++k) {
    const float w = G1[k * 128 + c];
    a0 = fmaf(x0[k], w, a0);
    a1 = fmaf(x1[k], w, a1);
    a2 = fmaf(x2[k], w, a2);
    a3 = fmaf(x3[k], w, a3);
  }
  tmpg[(size_t)(r0 + 0) * 128 + c] = fmaxf(a0, 0.f);
  tmpg[(size_t)(r0 + 1) * 128 + c] = fmaxf(a1, 0.f);
  tmpg[(size_t)(r0 + 2) * 128 + c] = fmaxf(a2, 0.f);
  tmpg[(size_t)(r0 + 3) * 128 + c] = fmaxf(a3, 0.f);
}

// ---------- kernel C2: out[C,256] = relu(tmpg @ G2 + gb2) ----------
__global__ __launch_bounds__(256) void k_g2(
    const float* __restrict__ tmpg, const float* __restrict__ G2,
    const float* __restrict__ gb2, float* __restrict__ out)
{
  const int c = threadIdx.x;                 // 0..255
  const int r0 = blockIdx.x * 8;
  float acc[8];
#pragma unroll
  for (int j = 0; j < 8; ++j) acc[j] = gb2[c];
#pragma unroll 2
  for (int k = 0; k < 128; ++k) {
    const float w = G2[k * 256 + c];
#pragma unroll
    for (int j = 0; j < 8; ++j)
      acc[j] = fmaf(tmpg[(size_t)(r0 + j) * 128 + k], w, acc[j]);
  }
#pragma unroll
  for (int j = 0; j < 8; ++j)
    out[(size_t)(r0 + j) * 256 + c] = fmaxf(acc[j], 0.f);
}

extern "C" void kernel_launch(void* const* d_in, const int* in_sizes, int n_in,
                              void* d_out, int out_size, void* d_ws, size_t ws_size,
                              hipStream_t stream)
{
  (void)in_sizes; (void)n_in; (void)out_size; (void)ws_size;
  const float* pts  = (const float*)d_in[0];
  const float* feat = (const float*)d_in[1];
  const int*   clus = (const int*)  d_in[2];
  const float* eW1  = (const float*)d_in[3];
  const float* eb1  = (const float*)d_in[4];
  const float* eW2  = (const float*)d_in[5];
  const float* eb2  = (const float*)d_in[6];
  const float* W1   = (const float*)d_in[7];
  const float* b1   = (const float*)d_in[8];
  const float* W2   = (const float*)d_in[9];
  const float* b2   = (const float*)d_in[10];
  const float* G1   = (const float*)d_in[11];
  const float* gb1  = (const float*)d_in[12];
  const float* G2   = (const float*)d_in[13];
  const float* gb2  = (const float*)d_in[14];
  float* out = (float*)d_out;

  // ws layout (floats): neigh[C*64] @0 | gmax[C*128] @262144 | cproj[C*128] @786432
  float* ws    = (float*)d_ws;
  float* neigh = ws;
  float* gmax  = ws + 262144;
  float* cproj = ws + 786432;
  float* tmpg  = cproj;                      // alias: cproj dead after k_main

  // zero neigh+gmax every call (atomicMax identity for relu'd values)
  hipMemsetAsync(d_ws, 0, (size_t)786432 * sizeof(float), stream);

  k_enc  <<<NN / 256, 256, 0, stream>>>(pts, clus, eW1, eb1, eW2, eb2, neigh);
  k_cproj<<<CC / 2,   256, 0, stream>>>(neigh, W1, b1, cproj);
  k_main <<<NN / 256, 256, 0, stream>>>(pts, feat, clus, W1, W2, b2, cproj, gmax);
  k_g1   <<<CC / 4,   128, 0, stream>>>(gmax, G1, gb1, tmpg);
  k_g2   <<<CC / 8,   256, 0, stream>>>(tmpg, G2, gb2, out);
}

// Round 2
// 2069.245 us; speedup vs baseline: 1.0769x; 1.0769x over previous
//
#include <hip/hip_runtime.h>

#define NN 262144
#define CC 4096

__device__ __forceinline__ unsigned short f_to_bf16u(float f) {
  union { float f; unsigned u; } v; v.f = f;
  unsigned u = v.u;
  u += 0x7fffu + ((u >> 16) & 1u);           // round-to-nearest-even
  return (unsigned short)(u >> 16);
}

// ---------- kernel A: enc MLP (3->32->64), segment-max via filtered atomicMax ----------
__global__ __launch_bounds__(256) void k_enc(
    const float* __restrict__ pts, const int* __restrict__ cluster,
    const float* __restrict__ eW1, const float* __restrict__ eb1,
    const float* __restrict__ eW2, const float* __restrict__ eb2,
    float* __restrict__ neigh)
{
  __shared__ float h1s[256 * 33];            // stride 33 words -> conflict-free
  const int t = threadIdx.x;
  const int i = blockIdx.x * 256 + t;
  const float p0 = pts[i * 3 + 0], p1 = pts[i * 3 + 1], p2 = pts[i * 3 + 2];
  float* hrow = h1s + t * 33;
#pragma unroll
  for (int c = 0; c < 32; ++c) {
    float a = fmaf(p2, eW1[64 + c], fmaf(p1, eW1[32 + c], fmaf(p0, eW1[c], eb1[c])));
    hrow[c] = fmaxf(a, 0.f);
  }
  float h2[64];
#pragma unroll
  for (int c = 0; c < 64; ++c) h2[c] = eb2[c];
#pragma unroll 4
  for (int k = 0; k < 32; ++k) {
    const float hk = hrow[k];
    const float* __restrict__ w = eW2 + k * 64;
#pragma unroll
    for (int c = 0; c < 64; ++c) h2[c] = fmaf(hk, w[c], h2[c]);
  }
  const int cid = cluster[i];
  int* dst = (int*)(neigh + (size_t)cid * 64);
  // monotone-safe filter: stored values only increase; stale read only
  // under-estimates -> skipping when vi <= read is always safe.
#pragma unroll
  for (int c = 0; c < 64; ++c) {
    const int vi = __float_as_int(h2[c]);
    if (vi > dst[c]) atomicMax(dst + c, vi);
  }
}

// ---------- kernel A2: cproj[C,128] = neigh @ W1[67:131] + b1 ----------
__global__ __launch_bounds__(256) void k_cproj(
    const float* __restrict__ neigh, const float* __restrict__ W1,
    const float* __restrict__ b1, float* __restrict__ cproj)
{
  const int c = threadIdx.x & 127;
  const int r = blockIdx.x * 2 + (threadIdx.x >> 7);
  const float* __restrict__ Wd = W1 + 67 * 128;
  const float* __restrict__ nr = neigh + r * 64;   // wave-uniform row
  float acc = b1[c];
#pragma unroll 8
  for (int k = 0; k < 64; ++k) acc = fmaf(nr[k], Wd[k * 128 + c], acc);
  cproj[r * 128 + c] = acc;
}

// ---------- kernel B: fc1(feat,pts,cproj-gather) + fc2, filtered segment-max ----------
__global__ __launch_bounds__(256) void k_main(
    const float* __restrict__ pts, const float* __restrict__ feat,
    const int* __restrict__ cluster,
    const float* __restrict__ W1, const float* __restrict__ W2,
    const float* __restrict__ b2, const float* __restrict__ cproj,
    float* __restrict__ gmax)
{
  __shared__ unsigned e1s[256 * 65];         // per-thread row, stride 65 u32 (pad)
  const int t = threadIdx.x;
  const int i = blockIdx.x * 256 + t;
  const float p0 = pts[i * 3 + 0], p1 = pts[i * 3 + 1], p2 = pts[i * 3 + 2];
  const int cid = cluster[i];
  const float* __restrict__ cp = cproj + (size_t)cid * 128;
  const float4* __restrict__ fr = reinterpret_cast<const float4*>(feat + (size_t)i * 64);
  const float* __restrict__ Wp = W1;          // rows 0..2  (points part)
  const float* __restrict__ Wf = W1 + 3 * 128; // rows 3..66 (features part)
  unsigned* __restrict__ rowu = e1s + t * 65;

  // ---- fc1: acc[128] = cp(=dup@Wd+b1) + pts@Wp + feat@Wf ----
  float acc[128];
#pragma unroll
  for (int c = 0; c < 128; ++c) acc[c] = cp[c];
#pragma unroll
  for (int c = 0; c < 128; ++c)
    acc[c] = fmaf(p2, Wp[256 + c], fmaf(p1, Wp[128 + c], fmaf(p0, Wp[c], acc[c])));
#pragma unroll 2
  for (int k4 = 0; k4 < 16; ++k4) {
    const float4 fv = fr[k4];
    const float* __restrict__ w0 = Wf + (4 * k4 + 0) * 128;
    const float* __restrict__ w1 = Wf + (4 * k4 + 1) * 128;
    const float* __restrict__ w2 = Wf + (4 * k4 + 2) * 128;
    const float* __restrict__ w3 = Wf + (4 * k4 + 3) * 128;
#pragma unroll
    for (int c = 0; c < 128; ++c) {
      acc[c] = fmaf(fv.x, w0[c], acc[c]);
      acc[c] = fmaf(fv.y, w1[c], acc[c]);
      acc[c] = fmaf(fv.z, w2[c], acc[c]);
      acc[c] = fmaf(fv.w, w3[c], acc[c]);
    }
  }
  // relu + pack bf16 pairs into own LDS row (no barrier needed: private row)
#pragma unroll
  for (int c = 0; c < 64; ++c) {
    const float a0 = fmaxf(acc[2 * c + 0], 0.f);
    const float a1 = fmaxf(acc[2 * c + 1], 0.f);
    rowu[c] = (unsigned)f_to_bf16u(a0) | ((unsigned)f_to_bf16u(a1) << 16);
  }

  // ---- fc2: 4 col-chunks of 32, k rolled over LDS-staged e1 ----
  int* gm = (int*)(gmax + (size_t)cid * 128);
#pragma unroll
  for (int ch = 0; ch < 4; ++ch) {
    const int cb = ch * 32;
    float a2[32];
#pragma unroll
    for (int c = 0; c < 32; ++c) a2[c] = b2[cb + c];
#pragma unroll 2
    for (int kk = 0; kk < 64; ++kk) {
      const unsigned u = rowu[kk];
      const float e0 = __uint_as_float(u << 16);
      const float e1 = __uint_as_float(u & 0xffff0000u);
      const float* __restrict__ w0 = W2 + (2 * kk + 0) * 128 + cb;
      const float* __restrict__ w1 = W2 + (2 * kk + 1) * 128 + cb;
#pragma unroll
      for (int c = 0; c < 32; ++c) {
        a2[c] = fmaf(e0, w0[c], a2[c]);
        a2[c] = fmaf(e1, w1[c], a2[c]);
      }
    }
    // monotone-safe filtered atomics (see k_enc comment)
#pragma unroll
    for (int c = 0; c < 32; ++c) {
      const int vi = __float_as_int(a2[c]);
      if (vi > gm[cb + c]) atomicMax(gm + cb + c, vi);
    }
  }
}

// ---------- kernel C1: tmpg[C,128] = relu(gmax @ G1 + gb1) ----------
__global__ __launch_bounds__(128) void k_g1(
    const float* __restrict__ gmax, const float* __restrict__ G1,
    const float* __restrict__ gb1, float* __restrict__ tmpg)
{
  const int c = threadIdx.x;                 // 0..127
  const int r0 = blockIdx.x * 4;
  const float* __restrict__ x0 = gmax + (size_t)(r0 + 0) * 128;
  const float* __restrict__ x1 = gmax + (size_t)(r0 + 1) * 128;
  const float* __restrict__ x2 = gmax + (size_t)(r0 + 2) * 128;
  const float* __restrict__ x3 = gmax + (size_t)(r0 + 3) * 128;
  float a0 = gb1[c], a1 = a0, a2 = a0, a3 = a0;
#pragma unroll 4
  for (int k = 0; k < 128; ++k) {
    const float w = G1[k * 128 + c];
    a0 = fmaf(x0[k], w, a0);
    a1 = fmaf(x1[k], w, a1);
    a2 = fmaf(x2[k], w, a2);
    a3 = fmaf(x3[k], w, a3);
  }
  tmpg[(size_t)(r0 + 0) * 128 + c] = fmaxf(a0, 0.f);
  tmpg[(size_t)(r0 + 1) * 128 + c] = fmaxf(a1, 0.f);
  tmpg[(size_t)(r0 + 2) * 128 + c] = fmaxf(a2, 0.f);
  tmpg[(size_t)(r0 + 3) * 128 + c] = fmaxf(a3, 0.f);
}

// ---------- kernel C2: out[C,256] = relu(tmpg @ G2 + gb2) ----------
__global__ __launch_bounds__(256) void k_g2(
    const float* __restrict__ tmpg, const float* __restrict__ G2,
    const float* __restrict__ gb2, float* __restrict__ out)
{
  const int c = threadIdx.x;                 // 0..255
  const int r0 = blockIdx.x * 8;
  float acc[8];
#pragma unroll
  for (int j = 0; j < 8; ++j) acc[j] = gb2[c];
#pragma unroll 2
  for (int k = 0; k < 128; ++k) {
    const float w = G2[k * 256 + c];
#pragma unroll
    for (int j = 0; j < 8; ++j)
      acc[j] = fmaf(tmpg[(size_t)(r0 + j) * 128 + k], w, acc[j]);
  }
#pragma unroll
  for (int j = 0; j < 8; ++j)
    out[(size_t)(r0 + j) * 256 + c] = fmaxf(acc[j], 0.f);
}

extern "C" void kernel_launch(void* const* d_in, const int* in_sizes, int n_in,
                              void* d_out, int out_size, void* d_ws, size_t ws_size,
                              hipStream_t stream)
{
  (void)in_sizes; (void)n_in; (void)out_size; (void)ws_size;
  const float* pts  = (const float*)d_in[0];
  const float* feat = (const float*)d_in[1];
  const int*   clus = (const int*)  d_in[2];
  const float* eW1  = (const float*)d_in[3];
  const float* eb1  = (const float*)d_in[4];
  const float* eW2  = (const float*)d_in[5];
  const float* eb2  = (const float*)d_in[6];
  const float* W1   = (const float*)d_in[7];
  const float* b1   = (const float*)d_in[8];
  const float* W2   = (const float*)d_in[9];
  const float* b2   = (const float*)d_in[10];
  const float* G1   = (const float*)d_in[11];
  const float* gb1  = (const float*)d_in[12];
  const float* G2   = (const float*)d_in[13];
  const float* gb2  = (const float*)d_in[14];
  float* out = (float*)d_out;

  // ws layout (floats): neigh[C*64] @0 | gmax[C*128] @262144 | cproj[C*128] @786432
  float* ws    = (float*)d_ws;
  float* neigh = ws;
  float* gmax  = ws + 262144;
  float* cproj = ws + 786432;
  float* tmpg  = cproj;                      // alias: cproj dead after k_main

  // zero neigh+gmax every call (atomicMax identity for relu'd values)
  hipMemsetAsync(d_ws, 0, (size_t)786432 * sizeof(float), stream);

  k_enc  <<<NN / 256, 256, 0, stream>>>(pts, clus, eW1, eb1, eW2, eb2, neigh);
  k_cproj<<<CC / 2,   256, 0, stream>>>(neigh, W1, b1, cproj);
  k_main <<<NN / 256, 256, 0, stream>>>(pts, feat, clus, W1, W2, b2, cproj, gmax);
  k_g1   <<<CC / 4,   128, 0, stream>>>(gmax, G1, gb1, tmpg);
  k_g2   <<<CC / 8,   256, 0, stream>>>(tmpg, G2, gb2, out);
}

// Round 3
// 503.689 us; speedup vs baseline: 4.4240x; 4.1082x over previous
//
#include <hip/hip_runtime.h>

#define NN 262144
#define CC 4096
#define NBLK 64              // sort blocks
#define PPB (NN / NBLK)      // 4096 points per sort block

__device__ __forceinline__ unsigned short f_to_bf16u(float f) {
  union { float f; unsigned u; } v; v.f = f;
  unsigned u = v.u;
  u += 0x7fffu + ((u >> 16) & 1u);           // round-to-nearest-even
  return (unsigned short)(u >> 16);
}

// ---------- sort 1: per-block LDS histogram ----------
__global__ __launch_bounds__(256) void k_hist(
    const int* __restrict__ cluster, unsigned* __restrict__ hist2d)
{
  __shared__ unsigned h[CC];
  const int t = threadIdx.x, b = blockIdx.x;
  for (int q = t; q < CC; q += 256) h[q] = 0u;
  __syncthreads();
  const int base = b * PPB;
#pragma unroll 4
  for (int k = 0; k < PPB; k += 256) atomicAdd(&h[cluster[base + k + t]], 1u);
  __syncthreads();
  for (int q = t; q < CC; q += 256) hist2d[b * CC + q] = h[q];
}

// ---------- sort 2: per-cluster exclusive scan over blocks ----------
__global__ __launch_bounds__(256) void k_scan_a(
    const unsigned* __restrict__ hist2d, unsigned* __restrict__ base2d,
    unsigned* __restrict__ totals)
{
  const int c = blockIdx.x * 256 + threadIdx.x;   // 0..4095
  unsigned acc = 0;
#pragma unroll 4
  for (int b = 0; b < NBLK; ++b) {
    const unsigned v = hist2d[b * CC + c];
    base2d[b * CC + c] = acc;
    acc += v;
  }
  totals[c] = acc;
}

// ---------- sort 3: exclusive scan of totals -> cstart ----------
__global__ __launch_bounds__(256) void k_scan_b(
    const unsigned* __restrict__ totals, unsigned* __restrict__ cstart)
{
  __shared__ unsigned part[256];
  const int t = threadIdx.x;
  unsigned loc[16];
  unsigned s = 0;
#pragma unroll
  for (int q = 0; q < 16; ++q) { loc[q] = s; s += totals[t * 16 + q]; }
  part[t] = s;
  __syncthreads();
  for (int off = 1; off < 256; off <<= 1) {
    const unsigned v = (t >= off) ? part[t - off] : 0u;
    __syncthreads();
    part[t] += v;
    __syncthreads();
  }
  const unsigned baset = part[t] - s;              // exclusive prefix for this thread
#pragma unroll
  for (int q = 0; q < 16; ++q) cstart[t * 16 + q] = baset + loc[q];
}

// ---------- sort 4: scatter via LDS cursors (order within cluster irrelevant) ----------
__global__ __launch_bounds__(256) void k_scatter(
    const int* __restrict__ cluster, const unsigned* __restrict__ base2d,
    const unsigned* __restrict__ cstart, unsigned* __restrict__ perm)
{
  __shared__ unsigned cur[CC];
  const int t = threadIdx.x, b = blockIdx.x;
  for (int q = t; q < CC; q += 256) cur[q] = base2d[b * CC + q] + cstart[q];
  __syncthreads();
  const int base = b * PPB;
#pragma unroll 4
  for (int k = 0; k < PPB; k += 256) {
    const int i = base + k + t;
    const unsigned pos = atomicAdd(&cur[cluster[i]], 1u);
    perm[pos] = (unsigned)i;
  }
}

// ---------- fused: enc -> pool -> cproj -> fc1+fc2 -> pool -> g1 -> g2 ----------
__global__ __launch_bounds__(64) void k_fused(
    const float* __restrict__ pts, const float* __restrict__ feat,
    const unsigned* __restrict__ perm, const unsigned* __restrict__ cstart,
    const unsigned* __restrict__ totals,
    const float* __restrict__ eW1, const float* __restrict__ eb1,
    const float* __restrict__ eW2, const float* __restrict__ eb2,
    const float* __restrict__ W1, const float* __restrict__ b1,
    const float* __restrict__ W2, const float* __restrict__ b2,
    const float* __restrict__ G1, const float* __restrict__ gb1,
    const float* __restrict__ G2, const float* __restrict__ gb2,
    float* __restrict__ out)
{
  __shared__ unsigned rowu[64 * 65];   // per-lane bf16x2 e1 row, stride 65 (pad)
  __shared__ float cp_lds[128];
  __shared__ float pooled[128];
  __shared__ float tg[128];
  const int lane = threadIdx.x;
  const int c = blockIdx.x;
  const int s0 = (int)cstart[c];
  const int sz = (int)totals[c];

  pooled[lane] = 0.f; pooled[lane + 64] = 0.f;   // max identity for relu'd vals

  // ---- phase E: enc MLP (3->32->64) per point, running per-lane max ----
  float nm[64];
#pragma unroll
  for (int q = 0; q < 64; ++q) nm[q] = 0.f;
  for (int j0 = 0; j0 < sz; j0 += 64) {
    const int j = j0 + lane;
    const bool act = j < sz;
    const int i = (int)perm[s0 + (act ? j : 0)];
    const float p0 = pts[i * 3 + 0], p1 = pts[i * 3 + 1], p2 = pts[i * 3 + 2];
    float h1[32];
#pragma unroll
    for (int q = 0; q < 32; ++q)
      h1[q] = fmaxf(fmaf(p2, eW1[64 + q], fmaf(p1, eW1[32 + q], fmaf(p0, eW1[q], eb1[q]))), 0.f);
    float h2[64];
#pragma unroll
    for (int q = 0; q < 64; ++q) h2[q] = eb2[q];
#pragma unroll 4
    for (int k = 0; k < 32; ++k) {
      const float hk = h1[k];
      const float* __restrict__ w = eW2 + k * 64;
#pragma unroll
      for (int q = 0; q < 64; ++q) h2[q] = fmaf(hk, w[q], h2[q]);
    }
#pragma unroll
    for (int q = 0; q < 64; ++q)
      nm[q] = fmaxf(nm[q], act ? fmaxf(h2[q], 0.f) : 0.f);
  }
  // butterfly max across the wave (all lanes end with cluster max)
#pragma unroll
  for (int rr = 0; rr < 6; ++rr) {
    const int r = 1 << rr;
#pragma unroll
    for (int q = 0; q < 64; ++q) nm[q] = fmaxf(nm[q], __shfl_xor(nm[q], r, 64));
  }

  // ---- phase C: cp = b1 + nm @ W1[67:131]  (2 cols/lane) ----
  {
    const float* __restrict__ Wd = W1 + 67 * 128;
    float c0 = b1[lane], c1 = b1[lane + 64];
#pragma unroll
    for (int k = 0; k < 64; ++k) {
      c0 = fmaf(nm[k], Wd[k * 128 + lane], c0);
      c1 = fmaf(nm[k], Wd[k * 128 + 64 + lane], c1);
    }
    cp_lds[lane] = c0; cp_lds[lane + 64] = c1;
  }
  __syncthreads();

  // ---- phase F: fc1 + fc2 per point, pooled into LDS ----
  unsigned* __restrict__ myrow = rowu + lane * 65;
  for (int j0 = 0; j0 < sz; j0 += 64) {
    const int j = j0 + lane;
    const bool act = j < sz;
    const int i = (int)perm[s0 + (act ? j : 0)];
    const float p0 = pts[i * 3 + 0], p1 = pts[i * 3 + 1], p2 = pts[i * 3 + 2];
    const float4* __restrict__ fr = reinterpret_cast<const float4*>(feat + (size_t)i * 64);
    float acc[128];
#pragma unroll
    for (int q = 0; q < 128; ++q) acc[q] = cp_lds[q];
#pragma unroll
    for (int q = 0; q < 128; ++q)
      acc[q] = fmaf(p2, W1[256 + q], fmaf(p1, W1[128 + q], fmaf(p0, W1[q], acc[q])));
#pragma unroll 2
    for (int k4 = 0; k4 < 16; ++k4) {
      const float4 fv = fr[k4];
      const float* __restrict__ w0 = W1 + (3 + 4 * k4 + 0) * 128;
      const float* __restrict__ w1 = W1 + (3 + 4 * k4 + 1) * 128;
      const float* __restrict__ w2 = W1 + (3 + 4 * k4 + 2) * 128;
      const float* __restrict__ w3 = W1 + (3 + 4 * k4 + 3) * 128;
#pragma unroll
      for (int q = 0; q < 128; ++q) {
        acc[q] = fmaf(fv.x, w0[q], acc[q]);
        acc[q] = fmaf(fv.y, w1[q], acc[q]);
        acc[q] = fmaf(fv.z, w2[q], acc[q]);
        acc[q] = fmaf(fv.w, w3[q], acc[q]);
      }
    }
    // relu + bf16-pack into private LDS row (enables dynamic k-index in fc2)
#pragma unroll
    for (int q = 0; q < 64; ++q) {
      const float a0 = fmaxf(acc[2 * q + 0], 0.f);
      const float a1 = fmaxf(acc[2 * q + 1], 0.f);
      myrow[q] = (unsigned)f_to_bf16u(a0) | ((unsigned)f_to_bf16u(a1) << 16);
    }
    // fc2 in 4 chunks of 32 cols; butterfly-max; lane0 folds into pooled
#pragma unroll
    for (int ch = 0; ch < 4; ++ch) {
      const int cb = ch * 32;
      float a2[32];
#pragma unroll
      for (int q = 0; q < 32; ++q) a2[q] = b2[cb + q];
#pragma unroll 2
      for (int kk = 0; kk < 64; ++kk) {
        const unsigned u = myrow[kk];
        const float e0 = __uint_as_float(u << 16);
        const float e1 = __uint_as_float(u & 0xffff0000u);
        const float* __restrict__ w0 = W2 + (2 * kk + 0) * 128 + cb;
        const float* __restrict__ w1 = W2 + (2 * kk + 1) * 128 + cb;
#pragma unroll
        for (int q = 0; q < 32; ++q) {
          a2[q] = fmaf(e0, w0[q], a2[q]);
          a2[q] = fmaf(e1, w1[q], a2[q]);
        }
      }
#pragma unroll
      for (int q = 0; q < 32; ++q) a2[q] = act ? fmaxf(a2[q], 0.f) : 0.f;
#pragma unroll
      for (int rr = 0; rr < 6; ++rr) {
        const int r = 1 << rr;
#pragma unroll
        for (int q = 0; q < 32; ++q) a2[q] = fmaxf(a2[q], __shfl_xor(a2[q], r, 64));
      }
      if (lane == 0) {
#pragma unroll
        for (int q = 0; q < 32; ++q) pooled[cb + q] = fmaxf(pooled[cb + q], a2[q]);
      }
    }
  }
  __syncthreads();

  // ---- phase G1: tg = relu(pooled @ G1 + gb1)  (2 cols/lane) ----
  {
    float t0 = gb1[lane], t1 = gb1[lane + 64];
#pragma unroll 4
    for (int k = 0; k < 128; ++k) {
      const float pv = pooled[k];
      t0 = fmaf(pv, G1[k * 128 + lane], t0);
      t1 = fmaf(pv, G1[k * 128 + 64 + lane], t1);
    }
    tg[lane] = fmaxf(t0, 0.f); tg[lane + 64] = fmaxf(t1, 0.f);
  }
  __syncthreads();

  // ---- phase G2: out = relu(tg @ G2 + gb2)  (4 cols/lane) ----
  {
    float o0 = gb2[lane], o1 = gb2[lane + 64], o2 = gb2[lane + 128], o3 = gb2[lane + 192];
#pragma unroll 4
    for (int k = 0; k < 128; ++k) {
      const float tv = tg[k];
      o0 = fmaf(tv, G2[k * 256 + lane], o0);
      o1 = fmaf(tv, G2[k * 256 + 64 + lane], o1);
      o2 = fmaf(tv, G2[k * 256 + 128 + lane], o2);
      o3 = fmaf(tv, G2[k * 256 + 192 + lane], o3);
    }
    float* __restrict__ orow = out + (size_t)c * 256;
    orow[lane] = fmaxf(o0, 0.f);
    orow[lane + 64] = fmaxf(o1, 0.f);
    orow[lane + 128] = fmaxf(o2, 0.f);
    orow[lane + 192] = fmaxf(o3, 0.f);
  }
}

extern "C" void kernel_launch(void* const* d_in, const int* in_sizes, int n_in,
                              void* d_out, int out_size, void* d_ws, size_t ws_size,
                              hipStream_t stream)
{
  (void)in_sizes; (void)n_in; (void)out_size; (void)ws_size;
  const float* pts  = (const float*)d_in[0];
  const float* feat = (const float*)d_in[1];
  const int*   clus = (const int*)  d_in[2];
  const float* eW1  = (const float*)d_in[3];
  const float* eb1  = (const float*)d_in[4];
  const float* eW2  = (const float*)d_in[5];
  const float* eb2  = (const float*)d_in[6];
  const float* W1   = (const float*)d_in[7];
  const float* b1   = (const float*)d_in[8];
  const float* W2   = (const float*)d_in[9];
  const float* b2   = (const float*)d_in[10];
  const float* G1   = (const float*)d_in[11];
  const float* gb1  = (const float*)d_in[12];
  const float* G2   = (const float*)d_in[13];
  const float* gb2  = (const float*)d_in[14];
  float* out = (float*)d_out;

  // ws layout (u32 units): hist2d[64*4096] @0 | base2d @262144 | totals @524288
  //                        cstart @528384 | perm @532480   (total ~3.0 MB)
  unsigned* ws      = (unsigned*)d_ws;
  unsigned* hist2d  = ws;
  unsigned* base2d  = ws + 262144;
  unsigned* totals  = ws + 524288;
  unsigned* cstart  = ws + 528384;
  unsigned* perm    = ws + 532480;

  k_hist   <<<NBLK, 256, 0, stream>>>(clus, hist2d);
  k_scan_a <<<CC / 256, 256, 0, stream>>>(hist2d, base2d, totals);
  k_scan_b <<<1, 256, 0, stream>>>(totals, cstart);
  k_scatter<<<NBLK, 256, 0, stream>>>(clus, base2d, cstart, perm);
  k_fused  <<<CC, 64, 0, stream>>>(pts, feat, perm, cstart, totals,
                                   eW1, eb1, eW2, eb2, W1, b1, W2, b2,
                                   G1, gb1, G2, gb2, out);
}

// Round 4
// 141.022 us; speedup vs baseline: 15.8011x; 3.5717x over previous
//
#include <hip/hip_runtime.h>

#define NN 262144
#define CC 4096
#define NBLK 64              // sort blocks
#define PPB (NN / NBLK)      // 4096 points per sort block

typedef __attribute__((ext_vector_type(8))) short bf16x8;
typedef __attribute__((ext_vector_type(4))) float f32x4;

__device__ __forceinline__ unsigned short f_to_bf16u(float f) {
  union { float f; unsigned u; } v; v.f = f;
  unsigned u = v.u;
  u += 0x7fffu + ((u >> 16) & 1u);           // round-to-nearest-even
  return (unsigned short)(u >> 16);
}
__device__ __forceinline__ unsigned pk2(float a, float b) {
  return (unsigned)f_to_bf16u(a) | ((unsigned)f_to_bf16u(b) << 16);
}

// ---------- sort 1: per-block LDS histogram ----------
__global__ __launch_bounds__(256) void k_hist(
    const int* __restrict__ cluster, unsigned* __restrict__ hist2d)
{
  __shared__ unsigned h[CC];
  const int t = threadIdx.x, b = blockIdx.x;
  for (int q = t; q < CC; q += 256) h[q] = 0u;
  __syncthreads();
  const int base = b * PPB;
#pragma unroll 4
  for (int k = 0; k < PPB; k += 256) atomicAdd(&h[cluster[base + k + t]], 1u);
  __syncthreads();
  for (int q = t; q < CC; q += 256) hist2d[b * CC + q] = h[q];
}

// ---------- sort 2: per-cluster exclusive scan over blocks ----------
__global__ __launch_bounds__(256) void k_scan_a(
    const unsigned* __restrict__ hist2d, unsigned* __restrict__ base2d,
    unsigned* __restrict__ totals)
{
  const int c = blockIdx.x * 256 + threadIdx.x;   // 0..4095
  unsigned acc = 0;
#pragma unroll 4
  for (int b = 0; b < NBLK; ++b) {
    const unsigned v = hist2d[b * CC + c];
    base2d[b * CC + c] = acc;
    acc += v;
  }
  totals[c] = acc;
}

// ---------- sort 3: exclusive scan of totals -> cstart ----------
__global__ __launch_bounds__(256) void k_scan_b(
    const unsigned* __restrict__ totals, unsigned* __restrict__ cstart)
{
  __shared__ unsigned part[256];
  const int t = threadIdx.x;
  unsigned loc[16];
  unsigned s = 0;
#pragma unroll
  for (int q = 0; q < 16; ++q) { loc[q] = s; s += totals[t * 16 + q]; }
  part[t] = s;
  __syncthreads();
  for (int off = 1; off < 256; off <<= 1) {
    const unsigned v = (t >= off) ? part[t - off] : 0u;
    __syncthreads();
    part[t] += v;
    __syncthreads();
  }
  const unsigned baset = part[t] - s;
#pragma unroll
  for (int q = 0; q < 16; ++q) cstart[t * 16 + q] = baset + loc[q];
}

// ---------- sort 4: scatter via LDS cursors ----------
__global__ __launch_bounds__(256) void k_scatter(
    const int* __restrict__ cluster, const unsigned* __restrict__ base2d,
    const unsigned* __restrict__ cstart, unsigned* __restrict__ perm)
{
  __shared__ unsigned cur[CC];
  const int t = threadIdx.x, b = blockIdx.x;
  for (int q = t; q < CC; q += 256) cur[q] = base2d[b * CC + q] + cstart[q];
  __syncthreads();
  const int base = b * PPB;
#pragma unroll 4
  for (int k = 0; k < PPB; k += 256) {
    const int i = base + k + t;
    const unsigned pos = atomicAdd(&cur[cluster[i]], 1u);
    perm[pos] = (unsigned)i;
  }
}

// ---------- prepack: weight B-fragments in exact MFMA lane order ----------
// B-frag mapping (16x16x32): col = nt*16 + (lane&15), k = (lane>>4)*8 + e.
// packE [4nt][64][4u32]  <- eW2[32][64]
// pack1 [3kk][8nt][64][4] <- X rows: k<64 -> W1[3+k], k=64..66 -> W1[k-64], else 0
// pack2 [4kk][8nt][64][4] <- W2[128][128]
__global__ __launch_bounds__(256) void k_pack(
    const float* __restrict__ eW2, const float* __restrict__ W1,
    const float* __restrict__ W2, unsigned* __restrict__ packE,
    unsigned* __restrict__ pack1, unsigned* __restrict__ pack2)
{
  const int id = blockIdx.x * 256 + threadIdx.x;
  if (id < 1024) {                                     // packE
    const int nt = id >> 8, l = (id >> 2) & 63, v = id & 3;
    const int k0 = (l >> 4) * 8 + 2 * v, col = nt * 16 + (l & 15);
    packE[id] = pk2(eW2[k0 * 64 + col], eW2[(k0 + 1) * 64 + col]);
  } else if (id < 1024 + 6144) {                       // pack1
    const int j = id - 1024;
    const int kk = j >> 11, nt = (j >> 8) & 7, l = (j >> 2) & 63, v = j & 3;
    const int col = nt * 16 + (l & 15);
    float vals[2];
#pragma unroll
    for (int h = 0; h < 2; ++h) {
      const int k = kk * 32 + (l >> 4) * 8 + 2 * v + h;
      vals[h] = (k < 64) ? W1[(3 + k) * 128 + col]
              : (k < 67) ? W1[(k - 64) * 128 + col] : 0.f;
    }
    pack1[j] = pk2(vals[0], vals[1]);
  } else if (id < 1024 + 6144 + 8192) {                // pack2
    const int j = id - (1024 + 6144);
    const int kk = j >> 11, nt = (j >> 8) & 7, l = (j >> 2) & 63, v = j & 3;
    const int col = nt * 16 + (l & 15);
    const int k0 = kk * 32 + (l >> 4) * 8 + 2 * v;
    pack2[j] = pk2(W2[k0 * 128 + col], W2[(k0 + 1) * 128 + col]);
  }
}

// ---------- fused per-cluster MFMA kernel ----------
__global__ __launch_bounds__(256) void k_fused(
    const float* __restrict__ pts, const float* __restrict__ feat,
    const unsigned* __restrict__ perm, const unsigned* __restrict__ cstart,
    const unsigned* __restrict__ totals,
    const float* __restrict__ eW1, const float* __restrict__ eb1,
    const float* __restrict__ eb2,
    const float* __restrict__ W1, const float* __restrict__ b1,
    const float* __restrict__ b2,
    const float* __restrict__ G1, const float* __restrict__ gb1,
    const float* __restrict__ G2, const float* __restrict__ gb2,
    const unsigned* __restrict__ packE, const unsigned* __restrict__ pack1,
    const unsigned* __restrict__ pack2, float* __restrict__ out)
{
  __shared__ unsigned h1s[64 * 20];   // h1 [64][40 bf16]  (pad 32->40: 2-way max)
  __shared__ unsigned fb [64 * 52];   // X  [64][104 bf16] (feat|pts|0, pad)
  __shared__ unsigned e1 [64 * 68];   // E1 [64][136 bf16]
  __shared__ float P4[64 * 4];
  __shared__ float nm[64];
  __shared__ float cp[128];
  __shared__ float pooled[128];
  __shared__ float tg[128];
  __shared__ float part[256];

  const int t = threadIdx.x;
  const int lane = t & 63, w = t >> 6;
  const int g = lane >> 4, ln15 = lane & 15;
  const int c = blockIdx.x;
  const int s0 = (int)cstart[c];
  const int sz = (int)totals[c];
  const int nch = (sz + 63) >> 6;

  if (t < 128) pooled[t] = 0.f;
  if (t < 64) {
    nm[t] = 0.f;
#pragma unroll
    for (int q = 0; q < 8; ++q) fb[t * 52 + 40 + q] = 0u;  // X cols 80..95 = 0
  }
  __syncthreads();

  // ================= pass 1: enc MLP + pool =================
  for (int ch = 0; ch < nch; ++ch) {
    const int base = s0 + ch * 64;
    const int szc = min(64, sz - ch * 64);
    if (t < 64) {
      const int rr = (t < szc) ? t : (szc - 1);
      const int i = (int)perm[base + rr];
      P4[t * 4 + 0] = pts[i * 3 + 0];
      P4[t * 4 + 1] = pts[i * 3 + 1];
      P4[t * 4 + 2] = pts[i * 3 + 2];
      P4[t * 4 + 3] = 0.f;
    }
    __syncthreads();
    {   // h1 = relu(P @ eW1 + eb1), bf16 to LDS; thread: row t>>2, 8 cols
      const int r = t >> 2, qq = t & 3;
      const float p0 = P4[r * 4], p1 = P4[r * 4 + 1], p2 = P4[r * 4 + 2];
      unsigned wv[4];
#pragma unroll
      for (int u = 0; u < 4; ++u) {
        float hv[2];
#pragma unroll
        for (int hh = 0; hh < 2; ++hh) {
          const int cc2 = qq * 8 + 2 * u + hh;
          hv[hh] = fmaxf(fmaf(p2, eW1[64 + cc2],
                         fmaf(p1, eW1[32 + cc2],
                         fmaf(p0, eW1[cc2], eb1[cc2]))), 0.f);
        }
        wv[u] = pk2(hv[0], hv[1]);
      }
      uint4 st; st.x = wv[0]; st.y = wv[1]; st.z = wv[2]; st.w = wv[3];
      *reinterpret_cast<uint4*>(&h1s[r * 20 + qq * 4]) = st;
    }
    __syncthreads();
    {   // enc MFMA: wave w -> cols 16w..16w+15 ; M=64, K=32
      const int col = w * 16 + ln15;
      const bf16x8 bfr = *reinterpret_cast<const bf16x8*>(&packE[(w * 64 + lane) * 4]);
      const float bias = eb2[col];
      f32x4 acc[4];
#pragma unroll
      for (int m = 0; m < 4; ++m) acc[m] = f32x4{bias, bias, bias, bias};
#pragma unroll
      for (int m = 0; m < 4; ++m) {
        const bf16x8 a = *reinterpret_cast<const bf16x8*>(&h1s[(16 * m + ln15) * 20 + g * 4]);
        acc[m] = __builtin_amdgcn_mfma_f32_16x16x32_bf16(a, bfr, acc[m], 0, 0, 0);
      }
      float vmax = 0.f;
#pragma unroll
      for (int m = 0; m < 4; ++m)
#pragma unroll
        for (int q = 0; q < 4; ++q) {
          const int row = 16 * m + 4 * g + q;
          vmax = fmaxf(vmax, (row < szc) ? fmaxf(acc[m][q], 0.f) : 0.f);
        }
      vmax = fmaxf(vmax, __shfl_xor(vmax, 16, 64));
      vmax = fmaxf(vmax, __shfl_xor(vmax, 32, 64));
      if (lane < 16) nm[col] = fmaxf(nm[col], vmax);
    }
    __syncthreads();
  }

  // ================= cproj: cp = b1 + nm @ W1[67:131] =================
  if (t < 128) {
    float a = b1[t];
    const float* __restrict__ Wd = W1 + 67 * 128;
#pragma unroll 4
    for (int j = 0; j < 16; ++j) {
      const f32x4 nv = *reinterpret_cast<const f32x4*>(&nm[4 * j]);
      a = fmaf(nv[0], Wd[(4 * j + 0) * 128 + t], a);
      a = fmaf(nv[1], Wd[(4 * j + 1) * 128 + t], a);
      a = fmaf(nv[2], Wd[(4 * j + 2) * 128 + t], a);
      a = fmaf(nv[3], Wd[(4 * j + 3) * 128 + t], a);
    }
    cp[t] = a;
  }
  __syncthreads();

  // ================= pass 2: fc1 -> fc2 -> pool =================
  for (int ch = 0; ch < nch; ++ch) {
    const int base = s0 + ch * 64;
    const int szc = min(64, sz - ch * 64);
    {   // stage X: feat cols 0..63 (4 threads/row, 16 cols each)
      const int r = t >> 2, seg = t & 3;
      const int rr = (r < szc) ? r : (szc - 1);
      const int i = (int)perm[base + rr];
      const float4* __restrict__ fp = reinterpret_cast<const float4*>(&feat[(size_t)i * 64 + seg * 16]);
      const float4 f0 = fp[0], f1 = fp[1], f2 = fp[2], f3 = fp[3];
      uint4 s0v, s1v;
      s0v.x = pk2(f0.x, f0.y); s0v.y = pk2(f0.z, f0.w);
      s0v.z = pk2(f1.x, f1.y); s0v.w = pk2(f1.z, f1.w);
      s1v.x = pk2(f2.x, f2.y); s1v.y = pk2(f2.z, f2.w);
      s1v.z = pk2(f3.x, f3.y); s1v.w = pk2(f3.z, f3.w);
      *reinterpret_cast<uint4*>(&fb[r * 52 + seg * 8 + 0]) = s0v;
      *reinterpret_cast<uint4*>(&fb[r * 52 + seg * 8 + 4]) = s1v;
    }
    if (t < 64) {    // X cols 64..79 = (p0,p1,p2,0...)
      const int rr = (t < szc) ? t : (szc - 1);
      const int i = (int)perm[base + rr];
      uint4 pw;
      pw.x = pk2(pts[i * 3 + 0], pts[i * 3 + 1]);
      pw.y = pk2(pts[i * 3 + 2], 0.f);
      pw.z = 0u; pw.w = 0u;
      *reinterpret_cast<uint4*>(&fb[t * 52 + 32]) = pw;
      uint4 zz; zz.x = zz.y = zz.z = zz.w = 0u;
      *reinterpret_cast<uint4*>(&fb[t * 52 + 36]) = zz;
    }
    __syncthreads();
    {   // fc1: M=64, N=32 (wave slice), K=96
      const float c0 = cp[w * 32 + ln15], c1 = cp[w * 32 + 16 + ln15];
      f32x4 acc0[4], acc1[4];
#pragma unroll
      for (int m = 0; m < 4; ++m) {
        acc0[m] = f32x4{c0, c0, c0, c0};
        acc1[m] = f32x4{c1, c1, c1, c1};
      }
#pragma unroll
      for (int kk = 0; kk < 3; ++kk) {
        const bf16x8 bf0 = *reinterpret_cast<const bf16x8*>(&pack1[((kk * 8 + 2 * w + 0) * 64 + lane) * 4]);
        const bf16x8 bf1 = *reinterpret_cast<const bf16x8*>(&pack1[((kk * 8 + 2 * w + 1) * 64 + lane) * 4]);
#pragma unroll
        for (int m = 0; m < 4; ++m) {
          const bf16x8 a = *reinterpret_cast<const bf16x8*>(&fb[(16 * m + ln15) * 52 + kk * 16 + g * 4]);
          acc0[m] = __builtin_amdgcn_mfma_f32_16x16x32_bf16(a, bf0, acc0[m], 0, 0, 0);
          acc1[m] = __builtin_amdgcn_mfma_f32_16x16x32_bf16(a, bf1, acc1[m], 0, 0, 0);
        }
      }
      // relu -> E1 bf16 (scatter u16 writes; rows>=szc hold dup-point values, masked later)
      unsigned short* __restrict__ e1b = reinterpret_cast<unsigned short*>(e1);
#pragma unroll
      for (int m = 0; m < 4; ++m)
#pragma unroll
        for (int q = 0; q < 4; ++q) {
          const int row = 16 * m + 4 * g + q;
          e1b[row * 136 + w * 32 + ln15]      = f_to_bf16u(fmaxf(acc0[m][q], 0.f));
          e1b[row * 136 + w * 32 + 16 + ln15] = f_to_bf16u(fmaxf(acc1[m][q], 0.f));
        }
    }
    __syncthreads();
    {   // fc2: M=64, N=32 (wave slice), K=128
      const float bb0 = b2[w * 32 + ln15], bb1 = b2[w * 32 + 16 + ln15];
      f32x4 acc0[4], acc1[4];
#pragma unroll
      for (int m = 0; m < 4; ++m) {
        acc0[m] = f32x4{bb0, bb0, bb0, bb0};
        acc1[m] = f32x4{bb1, bb1, bb1, bb1};
      }
#pragma unroll
      for (int kk = 0; kk < 4; ++kk) {
        const bf16x8 bf0 = *reinterpret_cast<const bf16x8*>(&pack2[((kk * 8 + 2 * w + 0) * 64 + lane) * 4]);
        const bf16x8 bf1 = *reinterpret_cast<const bf16x8*>(&pack2[((kk * 8 + 2 * w + 1) * 64 + lane) * 4]);
#pragma unroll
        for (int m = 0; m < 4; ++m) {
          const bf16x8 a = *reinterpret_cast<const bf16x8*>(&e1[(16 * m + ln15) * 68 + kk * 16 + g * 4]);
          acc0[m] = __builtin_amdgcn_mfma_f32_16x16x32_bf16(a, bf0, acc0[m], 0, 0, 0);
          acc1[m] = __builtin_amdgcn_mfma_f32_16x16x32_bf16(a, bf1, acc1[m], 0, 0, 0);
        }
      }
      float v0 = 0.f, v1 = 0.f;
#pragma unroll
      for (int m = 0; m < 4; ++m)
#pragma unroll
        for (int q = 0; q < 4; ++q) {
          const int row = 16 * m + 4 * g + q;
          const bool act = row < szc;
          v0 = fmaxf(v0, act ? fmaxf(acc0[m][q], 0.f) : 0.f);
          v1 = fmaxf(v1, act ? fmaxf(acc1[m][q], 0.f) : 0.f);
        }
      v0 = fmaxf(v0, __shfl_xor(v0, 16, 64)); v0 = fmaxf(v0, __shfl_xor(v0, 32, 64));
      v1 = fmaxf(v1, __shfl_xor(v1, 16, 64)); v1 = fmaxf(v1, __shfl_xor(v1, 32, 64));
      if (lane < 16) {
        pooled[w * 32 + lane]      = fmaxf(pooled[w * 32 + lane], v0);
        pooled[w * 32 + 16 + lane] = fmaxf(pooled[w * 32 + 16 + lane], v1);
      }
    }
    __syncthreads();
  }

  // ================= g1 (f32, split-K halves) =================
  {
    const int col = t & 127, half = t >> 7;
    float a = half ? 0.f : gb1[col];
#pragma unroll 2
    for (int j = 0; j < 16; ++j) {
      const f32x4 pv = *reinterpret_cast<const f32x4*>(&pooled[half * 64 + 4 * j]);
      a = fmaf(pv[0], G1[(half * 64 + 4 * j + 0) * 128 + col], a);
      a = fmaf(pv[1], G1[(half * 64 + 4 * j + 1) * 128 + col], a);
      a = fmaf(pv[2], G1[(half * 64 + 4 * j + 2) * 128 + col], a);
      a = fmaf(pv[3], G1[(half * 64 + 4 * j + 3) * 128 + col], a);
    }
    part[t] = a;
  }
  __syncthreads();
  if (t < 128) tg[t] = fmaxf(part[t] + part[t + 128], 0.f);
  __syncthreads();
  // ================= g2 (f32) =================
  {
    float a = gb2[t];
#pragma unroll 2
    for (int j = 0; j < 32; ++j) {
      const f32x4 tv = *reinterpret_cast<const f32x4*>(&tg[4 * j]);
      a = fmaf(tv[0], G2[(4 * j + 0) * 256 + t], a);
      a = fmaf(tv[1], G2[(4 * j + 1) * 256 + t], a);
      a = fmaf(tv[2], G2[(4 * j + 2) * 256 + t], a);
      a = fmaf(tv[3], G2[(4 * j + 3) * 256 + t], a);
    }
    out[(size_t)c * 256 + t] = fmaxf(a, 0.f);
  }
}

extern "C" void kernel_launch(void* const* d_in, const int* in_sizes, int n_in,
                              void* d_out, int out_size, void* d_ws, size_t ws_size,
                              hipStream_t stream)
{
  (void)in_sizes; (void)n_in; (void)out_size; (void)ws_size;
  const float* pts  = (const float*)d_in[0];
  const float* feat = (const float*)d_in[1];
  const int*   clus = (const int*)  d_in[2];
  const float* eW1  = (const float*)d_in[3];
  const float* eb1  = (const float*)d_in[4];
  const float* eW2  = (const float*)d_in[5];
  const float* eb2  = (const float*)d_in[6];
  const float* W1   = (const float*)d_in[7];
  const float* b1   = (const float*)d_in[8];
  const float* W2   = (const float*)d_in[9];
  const float* b2   = (const float*)d_in[10];
  const float* G1   = (const float*)d_in[11];
  const float* gb1  = (const float*)d_in[12];
  const float* G2   = (const float*)d_in[13];
  const float* gb2  = (const float*)d_in[14];
  float* out = (float*)d_out;

  // ws layout (u32): hist2d @0 | base2d @262144 | totals @524288 | cstart @528384
  //                  perm @532480 | packE @794624 | pack1 @795648 | pack2 @801792
  unsigned* ws      = (unsigned*)d_ws;
  unsigned* hist2d  = ws;
  unsigned* base2d  = ws + 262144;
  unsigned* totals  = ws + 524288;
  unsigned* cstart  = ws + 528384;
  unsigned* perm    = ws + 532480;
  unsigned* packE   = ws + 794624;
  unsigned* pack1   = ws + 795648;
  unsigned* pack2   = ws + 801792;

  k_hist   <<<NBLK, 256, 0, stream>>>(clus, hist2d);
  k_scan_a <<<CC / 256, 256, 0, stream>>>(hist2d, base2d, totals);
  k_scan_b <<<1, 256, 0, stream>>>(totals, cstart);
  k_scatter<<<NBLK, 256, 0, stream>>>(clus, base2d, cstart, perm);
  k_pack   <<<60, 256, 0, stream>>>(eW2, W1, W2, packE, pack1, pack2);
  k_fused  <<<CC, 256, 0, stream>>>(pts, feat, perm, cstart, totals,
                                    eW1, eb1, eb2, W1, b1, b2,
                                    G1, gb1, G2, gb2,
                                    packE, pack1, pack2, out);
}

// Round 5
// 125.262 us; speedup vs baseline: 17.7892x; 1.1258x over previous
//
#include <hip/hip_runtime.h>

#define NN 262144
#define CC 4096
#define NBLK 64              // sort blocks
#define PPB (NN / NBLK)      // 4096 points per sort block
#define NT (NN / 64)         // 4096 dense 64-row tiles
#define SLOTS 3              // per-cluster pooling slots (j>=2 -> atomic into slot 2)

typedef __attribute__((ext_vector_type(8))) short bf16x8;
typedef __attribute__((ext_vector_type(4))) float f32x4;

__device__ __forceinline__ unsigned short f_to_bf16u(float f) {
  union { float f; unsigned u; } v; v.f = f;
  unsigned u = v.u;
  u += 0x7fffu + ((u >> 16) & 1u);           // round-to-nearest-even
  return (unsigned short)(u >> 16);
}
__device__ __forceinline__ unsigned pk2(float a, float b) {
  return (unsigned)f_to_bf16u(a) | ((unsigned)f_to_bf16u(b) << 16);
}

// ---------- sort 1: per-block LDS histogram ----------
__global__ __launch_bounds__(256) void k_hist(
    const int* __restrict__ cluster, unsigned* __restrict__ hist2d)
{
  __shared__ unsigned h[CC];
  const int t = threadIdx.x, b = blockIdx.x;
  for (int q = t; q < CC; q += 256) h[q] = 0u;
  __syncthreads();
  const int base = b * PPB;
#pragma unroll 4
  for (int k = 0; k < PPB; k += 256) atomicAdd(&h[cluster[base + k + t]], 1u);
  __syncthreads();
  for (int q = t; q < CC; q += 256) hist2d[b * CC + q] = h[q];
}

// ---------- sort 2: per-cluster exclusive scan over blocks ----------
__global__ __launch_bounds__(256) void k_scan_a(
    const unsigned* __restrict__ hist2d, unsigned* __restrict__ base2d,
    unsigned* __restrict__ totals)
{
  const int c = blockIdx.x * 256 + threadIdx.x;
  unsigned acc = 0;
#pragma unroll 4
  for (int b = 0; b < NBLK; ++b) {
    const unsigned v = hist2d[b * CC + c];
    base2d[b * CC + c] = acc;
    acc += v;
  }
  totals[c] = acc;
}

// ---------- sort 3: exclusive scan of totals -> cstart ----------
__global__ __launch_bounds__(256) void k_scan_b(
    const unsigned* __restrict__ totals, unsigned* __restrict__ cstart)
{
  __shared__ unsigned part[256];
  const int t = threadIdx.x;
  unsigned loc[16];
  unsigned s = 0;
#pragma unroll
  for (int q = 0; q < 16; ++q) { loc[q] = s; s += totals[t * 16 + q]; }
  part[t] = s;
  __syncthreads();
  for (int off = 1; off < 256; off <<= 1) {
    const unsigned v = (t >= off) ? part[t - off] : 0u;
    __syncthreads();
    part[t] += v;
    __syncthreads();
  }
  const unsigned baset = part[t] - s;
#pragma unroll
  for (int q = 0; q < 16; ++q) cstart[t * 16 + q] = baset + loc[q];
}

// ---------- sort 4: scatter via LDS cursors (+ sorted cluster ids) ----------
__global__ __launch_bounds__(256) void k_scatter(
    const int* __restrict__ cluster, const unsigned* __restrict__ base2d,
    const unsigned* __restrict__ cstart, unsigned* __restrict__ perm,
    unsigned* __restrict__ scid)
{
  __shared__ unsigned cur[CC];
  const int t = threadIdx.x, b = blockIdx.x;
  for (int q = t; q < CC; q += 256) cur[q] = base2d[b * CC + q] + cstart[q];
  __syncthreads();
  const int base = b * PPB;
#pragma unroll 4
  for (int k = 0; k < PPB; k += 256) {
    const int i = base + k + t;
    const int c = cluster[i];
    const unsigned pos = atomicAdd(&cur[c], 1u);
    perm[pos] = (unsigned)i;
    scid[pos] = (unsigned)c;
  }
}

// ---------- prepack: weight B-fragments in exact MFMA lane order ----------
// B-frag (16x16x32): col = nt*16 + (lane&15), k-slot s = (lane>>4)*8 + e.
// packE: logical k order. pack1: logical (X stored in k order).
// pack2: INTERLEAVED k order matching E1 u32-pair storage:
//   storage s (even s0=2v) holds logical k0 = kk*32 + (l>>4)*4 + v ; s0+1 -> k0+16.
__global__ __launch_bounds__(256) void k_pack(
    const float* __restrict__ eW2, const float* __restrict__ W1,
    const float* __restrict__ W2, unsigned* __restrict__ packE,
    unsigned* __restrict__ pack1, unsigned* __restrict__ pack2)
{
  const int id = blockIdx.x * 256 + threadIdx.x;
  if (id < 1024) {                                     // packE
    const int nt = id >> 8, l = (id >> 2) & 63, v = id & 3;
    const int k0 = (l >> 4) * 8 + 2 * v, col = nt * 16 + (l & 15);
    packE[id] = pk2(eW2[k0 * 64 + col], eW2[(k0 + 1) * 64 + col]);
  } else if (id < 1024 + 6144) {                       // pack1
    const int j = id - 1024;
    const int kk = j >> 11, nt = (j >> 8) & 7, l = (j >> 2) & 63, v = j & 3;
    const int col = nt * 16 + (l & 15);
    float vals[2];
#pragma unroll
    for (int h = 0; h < 2; ++h) {
      const int k = kk * 32 + (l >> 4) * 8 + 2 * v + h;
      vals[h] = (k < 64) ? W1[(3 + k) * 128 + col]
              : (k < 67) ? W1[(k - 64) * 128 + col] : 0.f;
    }
    pack1[j] = pk2(vals[0], vals[1]);
  } else if (id < 1024 + 6144 + 8192) {                // pack2 (interleaved k)
    const int j = id - (1024 + 6144);
    const int kk = j >> 11, nt = (j >> 8) & 7, l = (j >> 2) & 63, v = j & 3;
    const int col = nt * 16 + (l & 15);
    const int k0 = kk * 32 + (l >> 4) * 4 + v;
    pack2[j] = pk2(W2[k0 * 128 + col], W2[(k0 + 16) * 128 + col]);
  }
}

// ---------- tile kernel 1: enc MLP (3->32->64) + segmented pool -> pse ----------
__global__ __launch_bounds__(256) void k_enc_t(
    const float* __restrict__ pts, const unsigned* __restrict__ perm,
    const unsigned* __restrict__ scid, const unsigned* __restrict__ cstart,
    const float* __restrict__ eW1, const float* __restrict__ eb1,
    const float* __restrict__ eb2, const unsigned* __restrict__ packE,
    float* __restrict__ pse)
{
  __shared__ float P4[64 * 4];
  __shared__ unsigned h1s[64 * 20];     // [64][40 bf16] pad -> 2-way max
  __shared__ int seg_r0[65];
  __shared__ int seg_cid[64];
  __shared__ int seg_j[64];
  __shared__ int nseg_s;
  const int t = threadIdx.x;
  const int lane = t & 63, w = t >> 6;
  const int g = lane >> 4, ln15 = lane & 15;
  const int b = blockIdx.x;

  if (w == 0) {   // segment table from sorted cluster ids
    const int cid = (int)scid[b * 64 + t];
    const bool flag = (t == 0) || ((int)scid[b * 64 + t - 1] != cid);
    const unsigned long long mask = __ballot(flag);
    const int rank = (int)__popcll(mask & ((1ull << t) - 1ull));
    if (flag) {
      seg_r0[rank] = t;
      seg_cid[rank] = cid;
      seg_j[rank] = b - (int)(cstart[cid] >> 6);
    }
    if (t == 0) {
      const int ns = (int)__popcll(mask);
      nseg_s = ns;
      seg_r0[ns] = 64;
    }
    const int i = (int)perm[b * 64 + t];
    P4[t * 4 + 0] = pts[i * 3 + 0];
    P4[t * 4 + 1] = pts[i * 3 + 1];
    P4[t * 4 + 2] = pts[i * 3 + 2];
    P4[t * 4 + 3] = 0.f;
  }
  __syncthreads();
  {   // h1 = relu(P @ eW1 + eb1) -> LDS bf16 ; thread: row t>>2, 8 cols
    const int r = t >> 2, qq = t & 3;
    const float p0 = P4[r * 4], p1 = P4[r * 4 + 1], p2 = P4[r * 4 + 2];
    unsigned wv[4];
#pragma unroll
    for (int u = 0; u < 4; ++u) {
      float hv[2];
#pragma unroll
      for (int hh = 0; hh < 2; ++hh) {
        const int cc2 = qq * 8 + 2 * u + hh;
        hv[hh] = fmaxf(fmaf(p2, eW1[64 + cc2],
                       fmaf(p1, eW1[32 + cc2],
                       fmaf(p0, eW1[cc2], eb1[cc2]))), 0.f);
      }
      wv[u] = pk2(hv[0], hv[1]);
    }
    uint4 st; st.x = wv[0]; st.y = wv[1]; st.z = wv[2]; st.w = wv[3];
    *reinterpret_cast<uint4*>(&h1s[r * 20 + qq * 4]) = st;
  }
  __syncthreads();
  {   // enc MFMA: wave w -> cols 16w..16w+15 ; M=64, K=32; segmented pool
    const int col = w * 16 + ln15;
    const bf16x8 bfr = *reinterpret_cast<const bf16x8*>(&packE[(w * 64 + lane) * 4]);
    const float bias = eb2[col];
    f32x4 acc[4];
#pragma unroll
    for (int m = 0; m < 4; ++m) acc[m] = f32x4{bias, bias, bias, bias};
#pragma unroll
    for (int m = 0; m < 4; ++m) {
      const bf16x8 a = *reinterpret_cast<const bf16x8*>(&h1s[(16 * m + ln15) * 20 + g * 4]);
      acc[m] = __builtin_amdgcn_mfma_f32_16x16x32_bf16(a, bfr, acc[m], 0, 0, 0);
    }
    const int nseg = nseg_s;
    for (int s = 0; s < nseg; ++s) {
      const int r0 = seg_r0[s], r1 = seg_r0[s + 1];
      float v = 0.f;
#pragma unroll
      for (int m = 0; m < 4; ++m)
#pragma unroll
        for (int q = 0; q < 4; ++q) {
          const int row = 16 * m + 4 * g + q;
          const bool in = (row >= r0) & (row < r1);
          v = fmaxf(v, in ? fmaxf(acc[m][q], 0.f) : 0.f);
        }
      v = fmaxf(v, __shfl_xor(v, 16, 64));
      v = fmaxf(v, __shfl_xor(v, 32, 64));
      if (lane < 16) {
        const int c = seg_cid[s], j = seg_j[s];
        if (j < SLOTS - 1)
          pse[((size_t)c * SLOTS + j) * 64 + col] = v;
        else
          atomicMax((int*)&pse[((size_t)c * SLOTS + (SLOTS - 1)) * 64 + col],
                    __float_as_int(v));
      }
    }
  }
}

// ---------- cproj: nm = max-combine(pse) ; cp = b1 + nm @ W1[67:131] ----------
__global__ __launch_bounds__(256) void k_cproj2(
    const float* __restrict__ pse, const float* __restrict__ W1,
    const float* __restrict__ b1, float* __restrict__ cproj)
{
  __shared__ float nm2[2][64];
  const int t = threadIdx.x, b = blockIdx.x;      // 2 clusters per block
  if (t < 128) {
    const int rr = t >> 6, col = t & 63;
    const float* p = pse + ((size_t)(b * 2 + rr) * SLOTS) * 64 + col;
    nm2[rr][col] = fmaxf(fmaxf(p[0], p[64]), p[128]);
  }
  __syncthreads();
  const int rr = t >> 7, col = t & 127;
  const float* __restrict__ Wd = W1 + 67 * 128;
  float a = b1[col];
#pragma unroll 4
  for (int j = 0; j < 16; ++j) {
    const f32x4 nv = *reinterpret_cast<const f32x4*>(&nm2[rr][4 * j]);
    a = fmaf(nv[0], Wd[(4 * j + 0) * 128 + col], a);
    a = fmaf(nv[1], Wd[(4 * j + 1) * 128 + col], a);
    a = fmaf(nv[2], Wd[(4 * j + 2) * 128 + col], a);
    a = fmaf(nv[3], Wd[(4 * j + 3) * 128 + col], a);
  }
  cproj[(size_t)(b * 2 + rr) * 128 + col] = a;
}

// ---------- tile kernel 2: fc1 + fc2 + segmented pool -> psf ----------
__global__ __launch_bounds__(256) void k_fc_t(
    const float* __restrict__ pts, const float* __restrict__ feat,
    const unsigned* __restrict__ perm, const unsigned* __restrict__ scid,
    const unsigned* __restrict__ cstart, const float* __restrict__ b2,
    const float* __restrict__ cproj, const unsigned* __restrict__ pack1,
    const unsigned* __restrict__ pack2, float* __restrict__ psf)
{
  __shared__ unsigned buf[64 * 68];   // X phase: [64][52] ; E1 phase: [64][68]
  __shared__ float cpd[16][128];
  __shared__ int ridx_l[64];
  __shared__ int cid_l[64];
  __shared__ int seg_r0[65];
  __shared__ int seg_cid[64];
  __shared__ int seg_j[64];
  __shared__ int nseg_s;
  const int t = threadIdx.x;
  const int lane = t & 63, w = t >> 6;
  const int g = lane >> 4, ln15 = lane & 15;
  const int b = blockIdx.x;

  if (w == 0) {   // segment table + per-row segment index
    const int cid = (int)scid[b * 64 + t];
    cid_l[t] = cid;
    const bool flag = (t == 0) || ((int)scid[b * 64 + t - 1] != cid);
    const unsigned long long mask = __ballot(flag);
    const int rank = (int)__popcll(mask & ((1ull << t) - 1ull));
    ridx_l[t] = (int)__popcll(mask & ((2ull << t) - 1ull)) - 1;
    if (flag) {
      seg_r0[rank] = t;
      seg_cid[rank] = cid;
      seg_j[rank] = b - (int)(cstart[cid] >> 6);
    }
    if (t == 0) {
      const int ns = (int)__popcll(mask);
      nseg_s = ns;
      seg_r0[ns] = 64;
    }
  }
  {   // stage X feat cols (bf16): 4 threads/row, 16 cols each
    const int r = t >> 2, seg = t & 3;
    const int i = (int)perm[b * 64 + r];
    const float4* __restrict__ fp = reinterpret_cast<const float4*>(&feat[(size_t)i * 64 + seg * 16]);
    const float4 f0 = fp[0], f1 = fp[1], f2 = fp[2], f3 = fp[3];
    uint4 s0v, s1v;
    s0v.x = pk2(f0.x, f0.y); s0v.y = pk2(f0.z, f0.w);
    s0v.z = pk2(f1.x, f1.y); s0v.w = pk2(f1.z, f1.w);
    s1v.x = pk2(f2.x, f2.y); s1v.y = pk2(f2.z, f2.w);
    s1v.z = pk2(f3.x, f3.y); s1v.w = pk2(f3.z, f3.w);
    *reinterpret_cast<uint4*>(&buf[r * 52 + seg * 8 + 0]) = s0v;
    *reinterpret_cast<uint4*>(&buf[r * 52 + seg * 8 + 4]) = s1v;
  }
  if (t < 64) {   // X cols 64..66 = pts, 67..95 = 0
    const int i = (int)perm[b * 64 + t];
    uint4 pw;
    pw.x = pk2(pts[i * 3 + 0], pts[i * 3 + 1]);
    pw.y = pk2(pts[i * 3 + 2], 0.f);
    pw.z = 0u; pw.w = 0u;
    uint4 zz; zz.x = zz.y = zz.z = zz.w = 0u;
    *reinterpret_cast<uint4*>(&buf[t * 52 + 32]) = pw;
    *reinterpret_cast<uint4*>(&buf[t * 52 + 36]) = zz;
    *reinterpret_cast<uint4*>(&buf[t * 52 + 40]) = zz;
    *reinterpret_cast<uint4*>(&buf[t * 52 + 44]) = zz;
  }
  __syncthreads();
  {   // stage distinct cproj rows
    const int nseg = nseg_s;
    const int lim = (nseg < 16) ? nseg : 16;
    for (int s = t >> 7; s < lim; s += 2)
      cpd[s][t & 127] = cproj[(size_t)seg_cid[s] * 128 + (t & 127)];
  }
  __syncthreads();

  const int colA = w * 32 + ln15, colB = colA + 16;
  f32x4 acc0[4], acc1[4];
  {   // fc1 init: per-row cluster projection
    const int nseg = nseg_s;
    if (nseg <= 2) {
      const float cA0 = cpd[0][colA], cA1 = cpd[0][colB];
      const float cB0 = (nseg == 2) ? cpd[1][colA] : cA0;
      const float cB1 = (nseg == 2) ? cpd[1][colB] : cA1;
      const int rb = (nseg == 2) ? seg_r0[1] : 64;
#pragma unroll
      for (int m = 0; m < 4; ++m)
#pragma unroll
        for (int q = 0; q < 4; ++q) {
          const int row = 16 * m + 4 * g + q;
          acc0[m][q] = (row < rb) ? cA0 : cB0;
          acc1[m][q] = (row < rb) ? cA1 : cB1;
        }
    } else {
#pragma unroll
      for (int m = 0; m < 4; ++m)
#pragma unroll
        for (int q = 0; q < 4; ++q) {
          const int row = 16 * m + 4 * g + q;
          const int idx = ridx_l[row];
          if (idx < 16) {
            acc0[m][q] = cpd[idx][colA];
            acc1[m][q] = cpd[idx][colB];
          } else {
            const int cc = cid_l[row];
            acc0[m][q] = cproj[(size_t)cc * 128 + colA];
            acc1[m][q] = cproj[(size_t)cc * 128 + colB];
          }
        }
    }
  }
  {   // fc1 MFMA: K=96
#pragma unroll
    for (int kk = 0; kk < 3; ++kk) {
      const bf16x8 bf0 = *reinterpret_cast<const bf16x8*>(&pack1[((kk * 8 + 2 * w + 0) * 64 + lane) * 4]);
      const bf16x8 bf1 = *reinterpret_cast<const bf16x8*>(&pack1[((kk * 8 + 2 * w + 1) * 64 + lane) * 4]);
#pragma unroll
      for (int m = 0; m < 4; ++m) {
        const bf16x8 a = *reinterpret_cast<const bf16x8*>(&buf[(16 * m + ln15) * 52 + kk * 16 + g * 4]);
        acc0[m] = __builtin_amdgcn_mfma_f32_16x16x32_bf16(a, bf0, acc0[m], 0, 0, 0);
        acc1[m] = __builtin_amdgcn_mfma_f32_16x16x32_bf16(a, bf1, acc1[m], 0, 0, 0);
      }
    }
  }
  __syncthreads();   // all X reads done; buf can be overwritten
  {   // E1 = relu(fc1) as interleaved bf16 pairs: u32 (col, col+16) -> conflict-free
#pragma unroll
    for (int m = 0; m < 4; ++m)
#pragma unroll
      for (int q = 0; q < 4; ++q) {
        const int row = 16 * m + 4 * g + q;
        buf[row * 68 + w * 16 + ln15] =
            pk2(fmaxf(acc0[m][q], 0.f), fmaxf(acc1[m][q], 0.f));
      }
  }
  __syncthreads();
  {   // fc2 MFMA: K=128 (interleaved k matches pack2)
    const float bb0 = b2[colA], bb1 = b2[colB];
#pragma unroll
    for (int m = 0; m < 4; ++m) {
      acc0[m] = f32x4{bb0, bb0, bb0, bb0};
      acc1[m] = f32x4{bb1, bb1, bb1, bb1};
    }
#pragma unroll
    for (int kk = 0; kk < 4; ++kk) {
      const bf16x8 bf0 = *reinterpret_cast<const bf16x8*>(&pack2[((kk * 8 + 2 * w + 0) * 64 + lane) * 4]);
      const bf16x8 bf1 = *reinterpret_cast<const bf16x8*>(&pack2[((kk * 8 + 2 * w + 1) * 64 + lane) * 4]);
#pragma unroll
      for (int m = 0; m < 4; ++m) {
        const bf16x8 a = *reinterpret_cast<const bf16x8*>(&buf[(16 * m + ln15) * 68 + kk * 16 + g * 4]);
        acc0[m] = __builtin_amdgcn_mfma_f32_16x16x32_bf16(a, bf0, acc0[m], 0, 0, 0);
        acc1[m] = __builtin_amdgcn_mfma_f32_16x16x32_bf16(a, bf1, acc1[m], 0, 0, 0);
      }
    }
  }
  {   // segmented pool -> psf
    const int nseg = nseg_s;
    for (int s = 0; s < nseg; ++s) {
      const int r0 = seg_r0[s], r1 = seg_r0[s + 1];
      float v0 = 0.f, v1 = 0.f;
#pragma unroll
      for (int m = 0; m < 4; ++m)
#pragma unroll
        for (int q = 0; q < 4; ++q) {
          const int row = 16 * m + 4 * g + q;
          const bool in = (row >= r0) & (row < r1);
          v0 = fmaxf(v0, in ? fmaxf(acc0[m][q], 0.f) : 0.f);
          v1 = fmaxf(v1, in ? fmaxf(acc1[m][q], 0.f) : 0.f);
        }
      v0 = fmaxf(v0, __shfl_xor(v0, 16, 64)); v0 = fmaxf(v0, __shfl_xor(v0, 32, 64));
      v1 = fmaxf(v1, __shfl_xor(v1, 16, 64)); v1 = fmaxf(v1, __shfl_xor(v1, 32, 64));
      if (lane < 16) {
        const int c = seg_cid[s], j = seg_j[s];
        if (j < SLOTS - 1) {
          psf[((size_t)c * SLOTS + j) * 128 + colA] = v0;
          psf[((size_t)c * SLOTS + j) * 128 + colB] = v1;
        } else {
          atomicMax((int*)&psf[((size_t)c * SLOTS + (SLOTS - 1)) * 128 + colA], __float_as_int(v0));
          atomicMax((int*)&psf[((size_t)c * SLOTS + (SLOTS - 1)) * 128 + colB], __float_as_int(v1));
        }
      }
    }
  }
}

// ---------- global stack: pooled = combine(psf) ; g1 ; g2 ----------
__global__ __launch_bounds__(256) void k_glob(
    const float* __restrict__ psf, const float* __restrict__ G1,
    const float* __restrict__ gb1, const float* __restrict__ G2,
    const float* __restrict__ gb2, float* __restrict__ out)
{
  __shared__ float pooled[128];
  __shared__ float part[256];
  __shared__ float tg[128];
  const int t = threadIdx.x, c = blockIdx.x;
  if (t < 128) {
    const float* p = psf + (size_t)c * SLOTS * 128 + t;
    pooled[t] = fmaxf(fmaxf(p[0], p[128]), p[256]);
  }
  __syncthreads();
  {
    const int col = t & 127, half = t >> 7;
    float a = half ? 0.f : gb1[col];
#pragma unroll 2
    for (int j = 0; j < 16; ++j) {
      const f32x4 pv = *reinterpret_cast<const f32x4*>(&pooled[half * 64 + 4 * j]);
      a = fmaf(pv[0], G1[(half * 64 + 4 * j + 0) * 128 + col], a);
      a = fmaf(pv[1], G1[(half * 64 + 4 * j + 1) * 128 + col], a);
      a = fmaf(pv[2], G1[(half * 64 + 4 * j + 2) * 128 + col], a);
      a = fmaf(pv[3], G1[(half * 64 + 4 * j + 3) * 128 + col], a);
    }
    part[t] = a;
  }
  __syncthreads();
  if (t < 128) tg[t] = fmaxf(part[t] + part[t + 128], 0.f);
  __syncthreads();
  {
    float a = gb2[t];
#pragma unroll 2
    for (int j = 0; j < 32; ++j) {
      const f32x4 tv = *reinterpret_cast<const f32x4*>(&tg[4 * j]);
      a = fmaf(tv[0], G2[(4 * j + 0) * 256 + t], a);
      a = fmaf(tv[1], G2[(4 * j + 1) * 256 + t], a);
      a = fmaf(tv[2], G2[(4 * j + 2) * 256 + t], a);
      a = fmaf(tv[3], G2[(4 * j + 3) * 256 + t], a);
    }
    out[(size_t)c * 256 + t] = fmaxf(a, 0.f);
  }
}

extern "C" void kernel_launch(void* const* d_in, const int* in_sizes, int n_in,
                              void* d_out, int out_size, void* d_ws, size_t ws_size,
                              hipStream_t stream)
{
  (void)in_sizes; (void)n_in; (void)out_size; (void)ws_size;
  const float* pts  = (const float*)d_in[0];
  const float* feat = (const float*)d_in[1];
  const int*   clus = (const int*)  d_in[2];
  const float* eW1  = (const float*)d_in[3];
  const float* eb1  = (const float*)d_in[4];
  const float* eW2  = (const float*)d_in[5];
  const float* eb2  = (const float*)d_in[6];
  const float* W1   = (const float*)d_in[7];
  const float* b1   = (const float*)d_in[8];
  const float* W2   = (const float*)d_in[9];
  const float* b2   = (const float*)d_in[10];
  const float* G1   = (const float*)d_in[11];
  const float* gb1  = (const float*)d_in[12];
  const float* G2   = (const float*)d_in[13];
  const float* gb2  = (const float*)d_in[14];
  float* out = (float*)d_out;

  // ws layout (u32 units):
  //   [0 .. 786432)        : sort phase hist2d(262144)+base2d(262144) ; later pse (4096*3*64)
  //   totals @786432 (4096) | cstart @790528 (4096)
  //   perm @794624 (262144) | scid @1056768 (262144)
  //   packE @1318912 (1024) | pack1 @1319936 (6144) | pack2 @1326080 (8192)
  //   cproj @1334272 (524288, f32)
  //   psf  @1858560 (4096*3*128 = 1572864, f32)      total ~13.1 MB
  unsigned* ws      = (unsigned*)d_ws;
  unsigned* hist2d  = ws;
  unsigned* base2d  = ws + 262144;
  float*    pse     = (float*)ws;
  unsigned* totals  = ws + 786432;
  unsigned* cstart  = ws + 790528;
  unsigned* perm    = ws + 794624;
  unsigned* scid    = ws + 1056768;
  unsigned* packE   = ws + 1318912;
  unsigned* pack1   = ws + 1319936;
  unsigned* pack2   = ws + 1326080;
  float*    cproj   = (float*)(ws + 1334272);
  float*    psf     = (float*)(ws + 1858560);

  k_hist   <<<NBLK, 256, 0, stream>>>(clus, hist2d);
  k_scan_a <<<CC / 256, 256, 0, stream>>>(hist2d, base2d, totals);
  k_scan_b <<<1, 256, 0, stream>>>(totals, cstart);
  k_scatter<<<NBLK, 256, 0, stream>>>(clus, base2d, cstart, perm, scid);
  k_pack   <<<60, 256, 0, stream>>>(eW2, W1, W2, packE, pack1, pack2);
  // zero pooling slots (after sort: pse aliases hist2d/base2d)
  hipMemsetAsync((void*)pse, 0, (size_t)786432 * 4, stream);
  hipMemsetAsync((void*)psf, 0, (size_t)1572864 * 4, stream);
  k_enc_t  <<<NT, 256, 0, stream>>>(pts, perm, scid, cstart, eW1, eb1, eb2, packE, pse);
  k_cproj2 <<<CC / 2, 256, 0, stream>>>(pse, W1, b1, cproj);
  k_fc_t   <<<NT, 256, 0, stream>>>(pts, feat, perm, scid, cstart, b2, cproj,
                                    pack1, pack2, psf);
  k_glob   <<<CC, 256, 0, stream>>>(psf, G1, gb1, G2, gb2, out);
}

// Round 6
// 118.990 us; speedup vs baseline: 18.7267x; 1.0527x over previous
//
#include <hip/hip_runtime.h>
#include <hip/hip_bf16.h>

#define NN 262144
#define CC 4096
#define NBLK 64              // sort blocks
#define PPB (NN / NBLK)      // 4096 points per sort block
#define NT (NN / 64)         // 4096 dense 64-row tiles
#define SLOTS 3              // per-cluster pooling slots (j>=2 -> atomic into slot 2)

typedef __attribute__((ext_vector_type(8))) short bf16x8;
typedef __attribute__((ext_vector_type(4))) float f32x4;

// bf16 pair pack via HW cvt (compiler emits v_cvt_pk_bf16_f32 / v_cvt ops; RNE)
__device__ __forceinline__ unsigned pk2(float a, float b) {
  __hip_bfloat16 ha = __float2bfloat16(a);
  __hip_bfloat16 hb = __float2bfloat16(b);
  unsigned short ua, ub;
  __builtin_memcpy(&ua, &ha, 2);
  __builtin_memcpy(&ub, &hb, 2);
  return (unsigned)ua | ((unsigned)ub << 16);
}

// ---------- fused init: blocks 0..63 = per-block histogram ; 64..123 = weight prepack ----------
// B-frag (16x16x32): col = nt*16 + (lane&15), k-slot s = (lane>>4)*8 + e.
// packE: logical k order. pack1: logical. pack2: INTERLEAVED k order matching E1
// u32-pair storage: even slot s0=2v holds k0 = kk*32 + (l>>4)*4 + v ; s0+1 -> k0+16.
__global__ __launch_bounds__(256) void k_init(
    const int* __restrict__ cluster, unsigned* __restrict__ hist2d,
    const float* __restrict__ eW2, const float* __restrict__ W1,
    const float* __restrict__ W2, unsigned* __restrict__ packE,
    unsigned* __restrict__ pack1, unsigned* __restrict__ pack2)
{
  __shared__ unsigned h[CC];
  const int t = threadIdx.x, b = blockIdx.x;
  if (b < NBLK) {                                      // histogram
    for (int q = t; q < CC; q += 256) h[q] = 0u;
    __syncthreads();
    const int base = b * PPB;
#pragma unroll 4
    for (int k = 0; k < PPB; k += 256) atomicAdd(&h[cluster[base + k + t]], 1u);
    __syncthreads();
    for (int q = t; q < CC; q += 256) hist2d[b * CC + q] = h[q];
    return;
  }
  const int id = (b - NBLK) * 256 + t;                 // prepack
  if (id < 1024) {                                     // packE
    const int nt = id >> 8, l = (id >> 2) & 63, v = id & 3;
    const int k0 = (l >> 4) * 8 + 2 * v, col = nt * 16 + (l & 15);
    packE[id] = pk2(eW2[k0 * 64 + col], eW2[(k0 + 1) * 64 + col]);
  } else if (id < 1024 + 6144) {                       // pack1
    const int j = id - 1024;
    const int kk = j >> 11, nt = (j >> 8) & 7, l = (j >> 2) & 63, v = j & 3;
    const int col = nt * 16 + (l & 15);
    float vals[2];
#pragma unroll
    for (int hh = 0; hh < 2; ++hh) {
      const int k = kk * 32 + (l >> 4) * 8 + 2 * v + hh;
      vals[hh] = (k < 64) ? W1[(3 + k) * 128 + col]
               : (k < 67) ? W1[(k - 64) * 128 + col] : 0.f;
    }
    pack1[j] = pk2(vals[0], vals[1]);
  } else {                                             // pack2 (interleaved k)
    const int j = id - (1024 + 6144);
    const int kk = j >> 11, nt = (j >> 8) & 7, l = (j >> 2) & 63, v = j & 3;
    const int col = nt * 16 + (l & 15);
    const int k0 = kk * 32 + (l >> 4) * 4 + v;
    pack2[j] = pk2(W2[k0 * 128 + col], W2[(k0 + 16) * 128 + col]);
  }
}

// ---------- scan_a: blocks 0..15 per-cluster scan over sort blocks ; 16..63 zero psf ----------
__global__ __launch_bounds__(256) void k_scan_a(
    const unsigned* __restrict__ hist2d, unsigned* __restrict__ base2d,
    unsigned* __restrict__ totals, float4* __restrict__ psf4)
{
  const int t = threadIdx.x, b = blockIdx.x;
  if (b < 16) {
    const int c = b * 256 + t;
    unsigned acc = 0;
#pragma unroll 4
    for (int bb = 0; bb < NBLK; ++bb) {
      const unsigned v = hist2d[bb * CC + c];
      base2d[bb * CC + c] = acc;
      acc += v;
    }
    totals[c] = acc;
  } else {                                             // zero psf: 48 blocks x 8192 float4
    const int zb = b - 16;
    const float4 z = {0.f, 0.f, 0.f, 0.f};
    float4* __restrict__ p = psf4 + (size_t)zb * 8192 + t;
#pragma unroll 8
    for (int q = 0; q < 32; ++q) p[q * 256] = z;
  }
}

// ---------- scatter (inline cstart scan; block 0 publishes cstart) ----------
__global__ __launch_bounds__(256) void k_scatter(
    const int* __restrict__ cluster, const unsigned* __restrict__ base2d,
    const unsigned* __restrict__ totals, unsigned* __restrict__ perm,
    unsigned* __restrict__ scid, unsigned* __restrict__ cstart_g)
{
  __shared__ unsigned cur[CC];
  __shared__ unsigned part[256];
  const int t = threadIdx.x, b = blockIdx.x;
  unsigned loc[16];
  unsigned s = 0;
#pragma unroll
  for (int q = 0; q < 16; ++q) { loc[q] = s; s += totals[t * 16 + q]; }
  part[t] = s;
  __syncthreads();
  for (int off = 1; off < 256; off <<= 1) {
    const unsigned v = (t >= off) ? part[t - off] : 0u;
    __syncthreads();
    part[t] += v;
    __syncthreads();
  }
  const unsigned baset = part[t] - s;
#pragma unroll
  for (int q = 0; q < 16; ++q) {
    const unsigned cs = baset + loc[q];
    cur[t * 16 + q] = base2d[b * CC + t * 16 + q] + cs;
    if (b == 0) cstart_g[t * 16 + q] = cs;
  }
  __syncthreads();
  const int base = b * PPB;
#pragma unroll 4
  for (int k = 0; k < PPB; k += 256) {
    const int i = base + k + t;
    const int c = cluster[i];
    const unsigned pos = atomicAdd(&cur[c], 1u);
    perm[pos] = (unsigned)i;
    scid[pos] = (unsigned)c;
  }
}

// ---------- tile kernel 1: enc MLP (3->32->64) + segmented pool -> pse ----------
__global__ __launch_bounds__(256) void k_enc_t(
    const float* __restrict__ pts, const unsigned* __restrict__ perm,
    const unsigned* __restrict__ scid, const unsigned* __restrict__ cstart,
    const float* __restrict__ eW1, const float* __restrict__ eb1,
    const float* __restrict__ eb2, const unsigned* __restrict__ packE,
    float* __restrict__ pse)
{
  __shared__ float P4[64 * 4];
  __shared__ unsigned h1s[64 * 20];     // [64][40 bf16] pad -> 2-way max
  __shared__ int seg_r0[65];
  __shared__ int seg_cid[64];
  __shared__ int seg_j[64];
  __shared__ int nseg_s;
  const int t = threadIdx.x;
  const int lane = t & 63, w = t >> 6;
  const int g = lane >> 4, ln15 = lane & 15;
  const int b = blockIdx.x;

  if (w == 0) {   // segment table from sorted cluster ids
    const int cid = (int)scid[b * 64 + t];
    const bool flag = (t == 0) || ((int)scid[b * 64 + t - 1] != cid);
    const unsigned long long mask = __ballot(flag);
    const int rank = (int)__popcll(mask & ((1ull << t) - 1ull));
    if (flag) {
      seg_r0[rank] = t;
      seg_cid[rank] = cid;
      seg_j[rank] = b - (int)(cstart[cid] >> 6);
    }
    if (t == 0) {
      const int ns = (int)__popcll(mask);
      nseg_s = ns;
      seg_r0[ns] = 64;
    }
    const int i = (int)perm[b * 64 + t];
    P4[t * 4 + 0] = pts[i * 3 + 0];
    P4[t * 4 + 1] = pts[i * 3 + 1];
    P4[t * 4 + 2] = pts[i * 3 + 2];
    P4[t * 4 + 3] = 0.f;
  }
  __syncthreads();
  {   // h1 = relu(P @ eW1 + eb1) -> LDS bf16 ; thread: row t>>2, 8 cols
    const int r = t >> 2, qq = t & 3;
    const float p0 = P4[r * 4], p1 = P4[r * 4 + 1], p2 = P4[r * 4 + 2];
    unsigned wv[4];
#pragma unroll
    for (int u = 0; u < 4; ++u) {
      float hv[2];
#pragma unroll
      for (int hh = 0; hh < 2; ++hh) {
        const int cc2 = qq * 8 + 2 * u + hh;
        hv[hh] = fmaxf(fmaf(p2, eW1[64 + cc2],
                       fmaf(p1, eW1[32 + cc2],
                       fmaf(p0, eW1[cc2], eb1[cc2]))), 0.f);
      }
      wv[u] = pk2(hv[0], hv[1]);
    }
    uint4 st; st.x = wv[0]; st.y = wv[1]; st.z = wv[2]; st.w = wv[3];
    *reinterpret_cast<uint4*>(&h1s[r * 20 + qq * 4]) = st;
  }
  __syncthreads();
  {   // enc MFMA: wave w -> cols 16w..16w+15 ; M=64, K=32; segmented pool
    const int col = w * 16 + ln15;
    const bf16x8 bfr = *reinterpret_cast<const bf16x8*>(&packE[(w * 64 + lane) * 4]);
    const float bias = eb2[col];
    f32x4 acc[4];
#pragma unroll
    for (int m = 0; m < 4; ++m) acc[m] = f32x4{bias, bias, bias, bias};
#pragma unroll
    for (int m = 0; m < 4; ++m) {
      const bf16x8 a = *reinterpret_cast<const bf16x8*>(&h1s[(16 * m + ln15) * 20 + g * 4]);
      acc[m] = __builtin_amdgcn_mfma_f32_16x16x32_bf16(a, bfr, acc[m], 0, 0, 0);
    }
    const int nseg = nseg_s;
    for (int s = 0; s < nseg; ++s) {
      const int r0 = seg_r0[s], r1 = seg_r0[s + 1];
      float v = 0.f;
#pragma unroll
      for (int m = 0; m < 4; ++m)
#pragma unroll
        for (int q = 0; q < 4; ++q) {
          const int row = 16 * m + 4 * g + q;
          const bool in = (row >= r0) & (row < r1);
          v = fmaxf(v, in ? fmaxf(acc[m][q], 0.f) : 0.f);
        }
      v = fmaxf(v, __shfl_xor(v, 16, 64));
      v = fmaxf(v, __shfl_xor(v, 32, 64));
      if (lane < 16) {
        const int c = seg_cid[s], j = seg_j[s];
        if (j < SLOTS - 1)
          pse[((size_t)c * SLOTS + j) * 64 + col] = v;
        else
          atomicMax((int*)&pse[((size_t)c * SLOTS + (SLOTS - 1)) * 64 + col],
                    __float_as_int(v));
      }
    }
  }
}

// ---------- cproj: nm = max-combine(pse) ; cp = b1 + nm @ W1[67:131] ----------
__global__ __launch_bounds__(256) void k_cproj2(
    const float* __restrict__ pse, const float* __restrict__ W1,
    const float* __restrict__ b1, float* __restrict__ cproj)
{
  __shared__ float nm2[2][64];
  const int t = threadIdx.x, b = blockIdx.x;      // 2 clusters per block
  if (t < 128) {
    const int rr = t >> 6, col = t & 63;
    const float* p = pse + ((size_t)(b * 2 + rr) * SLOTS) * 64 + col;
    nm2[rr][col] = fmaxf(fmaxf(p[0], p[64]), p[128]);
  }
  __syncthreads();
  const int rr = t >> 7, col = t & 127;
  const float* __restrict__ Wd = W1 + 67 * 128;
  float a = b1[col];
#pragma unroll 4
  for (int j = 0; j < 16; ++j) {
    const f32x4 nv = *reinterpret_cast<const f32x4*>(&nm2[rr][4 * j]);
    a = fmaf(nv[0], Wd[(4 * j + 0) * 128 + col], a);
    a = fmaf(nv[1], Wd[(4 * j + 1) * 128 + col], a);
    a = fmaf(nv[2], Wd[(4 * j + 2) * 128 + col], a);
    a = fmaf(nv[3], Wd[(4 * j + 3) * 128 + col], a);
  }
  cproj[(size_t)(b * 2 + rr) * 128 + col] = a;
}

// ---------- tile kernel 2: fc1 + fc2 + segmented pool -> psf ----------
__global__ __launch_bounds__(256) void k_fc_t(
    const float* __restrict__ pts, const float* __restrict__ feat,
    const unsigned* __restrict__ perm, const unsigned* __restrict__ scid,
    const unsigned* __restrict__ cstart, const float* __restrict__ b2,
    const float* __restrict__ cproj, const unsigned* __restrict__ pack1,
    const unsigned* __restrict__ pack2, float* __restrict__ psf)
{
  __shared__ unsigned buf[64 * 68];   // X phase: [64][52] ; E1 phase: [64][68]
  __shared__ float cpd[8][128];
  __shared__ int ridx_l[64];
  __shared__ int cid_l[64];
  __shared__ int seg_r0[65];
  __shared__ int seg_cid[64];
  __shared__ int seg_j[64];
  __shared__ int nseg_s;
  const int t = threadIdx.x;
  const int lane = t & 63, w = t >> 6;
  const int g = lane >> 4, ln15 = lane & 15;
  const int b = blockIdx.x;

  if (w == 0) {   // segment table + per-row segment index
    const int cid = (int)scid[b * 64 + t];
    cid_l[t] = cid;
    const bool flag = (t == 0) || ((int)scid[b * 64 + t - 1] != cid);
    const unsigned long long mask = __ballot(flag);
    const int rank = (int)__popcll(mask & ((1ull << t) - 1ull));
    ridx_l[t] = (int)__popcll(mask & ((2ull << t) - 1ull)) - 1;
    if (flag) {
      seg_r0[rank] = t;
      seg_cid[rank] = cid;
      seg_j[rank] = b - (int)(cstart[cid] >> 6);
    }
    if (t == 0) {
      const int ns = (int)__popcll(mask);
      nseg_s = ns;
      seg_r0[ns] = 64;
    }
  }
  {   // stage X feat cols (bf16): 4 threads/row, 16 cols each
    const int r = t >> 2, seg = t & 3;
    const int i = (int)perm[b * 64 + r];
    const float4* __restrict__ fp = reinterpret_cast<const float4*>(&feat[(size_t)i * 64 + seg * 16]);
    const float4 f0 = fp[0], f1 = fp[1], f2 = fp[2], f3 = fp[3];
    uint4 s0v, s1v;
    s0v.x = pk2(f0.x, f0.y); s0v.y = pk2(f0.z, f0.w);
    s0v.z = pk2(f1.x, f1.y); s0v.w = pk2(f1.z, f1.w);
    s1v.x = pk2(f2.x, f2.y); s1v.y = pk2(f2.z, f2.w);
    s1v.z = pk2(f3.x, f3.y); s1v.w = pk2(f3.z, f3.w);
    *reinterpret_cast<uint4*>(&buf[r * 52 + seg * 8 + 0]) = s0v;
    *reinterpret_cast<uint4*>(&buf[r * 52 + seg * 8 + 4]) = s1v;
  }
  if (t < 64) {   // X cols 64..66 = pts, 67..95 = 0
    const int i = (int)perm[b * 64 + t];
    uint4 pw;
    pw.x = pk2(pts[i * 3 + 0], pts[i * 3 + 1]);
    pw.y = pk2(pts[i * 3 + 2], 0.f);
    pw.z = 0u; pw.w = 0u;
    uint4 zz; zz.x = zz.y = zz.z = zz.w = 0u;
    *reinterpret_cast<uint4*>(&buf[t * 52 + 32]) = pw;
    *reinterpret_cast<uint4*>(&buf[t * 52 + 36]) = zz;
    *reinterpret_cast<uint4*>(&buf[t * 52 + 40]) = zz;
    *reinterpret_cast<uint4*>(&buf[t * 52 + 44]) = zz;
  }
  __syncthreads();
  {   // stage distinct cproj rows (fallback to global for seg idx >= 8)
    const int nseg = nseg_s;
    const int lim = (nseg < 8) ? nseg : 8;
    for (int s = t >> 7; s < lim; s += 2)
      cpd[s][t & 127] = cproj[(size_t)seg_cid[s] * 128 + (t & 127)];
  }
  __syncthreads();

  const int colA = w * 32 + ln15, colB = colA + 16;
  f32x4 acc0[4], acc1[4];
  {   // fc1 init: per-row cluster projection
    const int nseg = nseg_s;
    if (nseg <= 2) {
      const float cA0 = cpd[0][colA], cA1 = cpd[0][colB];
      const float cB0 = (nseg == 2) ? cpd[1][colA] : cA0;
      const float cB1 = (nseg == 2) ? cpd[1][colB] : cA1;
      const int rb = (nseg == 2) ? seg_r0[1] : 64;
#pragma unroll
      for (int m = 0; m < 4; ++m)
#pragma unroll
        for (int q = 0; q < 4; ++q) {
          const int row = 16 * m + 4 * g + q;
          acc0[m][q] = (row < rb) ? cA0 : cB0;
          acc1[m][q] = (row < rb) ? cA1 : cB1;
        }
    } else {
#pragma unroll
      for (int m = 0; m < 4; ++m)
#pragma unroll
        for (int q = 0; q < 4; ++q) {
          const int row = 16 * m + 4 * g + q;
          const int idx = ridx_l[row];
          if (idx < 8) {
            acc0[m][q] = cpd[idx][colA];
            acc1[m][q] = cpd[idx][colB];
          } else {
            const int cc = cid_l[row];
            acc0[m][q] = cproj[(size_t)cc * 128 + colA];
            acc1[m][q] = cproj[(size_t)cc * 128 + colB];
          }
        }
    }
  }
  {   // fc1 MFMA: K=96
#pragma unroll
    for (int kk = 0; kk < 3; ++kk) {
      const bf16x8 bf0 = *reinterpret_cast<const bf16x8*>(&pack1[((kk * 8 + 2 * w + 0) * 64 + lane) * 4]);
      const bf16x8 bf1 = *reinterpret_cast<const bf16x8*>(&pack1[((kk * 8 + 2 * w + 1) * 64 + lane) * 4]);
#pragma unroll
      for (int m = 0; m < 4; ++m) {
        const bf16x8 a = *reinterpret_cast<const bf16x8*>(&buf[(16 * m + ln15) * 52 + kk * 16 + g * 4]);
        acc0[m] = __builtin_amdgcn_mfma_f32_16x16x32_bf16(a, bf0, acc0[m], 0, 0, 0);
        acc1[m] = __builtin_amdgcn_mfma_f32_16x16x32_bf16(a, bf1, acc1[m], 0, 0, 0);
      }
    }
  }
  __syncthreads();   // all X reads done; buf can be overwritten
  {   // E1 = relu(fc1) as interleaved bf16 pairs: u32 (col, col+16) -> conflict-free
#pragma unroll
    for (int m = 0; m < 4; ++m)
#pragma unroll
      for (int q = 0; q < 4; ++q) {
        const int row = 16 * m + 4 * g + q;
        buf[row * 68 + w * 16 + ln15] =
            pk2(fmaxf(acc0[m][q], 0.f), fmaxf(acc1[m][q], 0.f));
      }
  }
  __syncthreads();
  {   // fc2 MFMA: K=128 (interleaved k matches pack2)
    const float bb0 = b2[colA], bb1 = b2[colB];
#pragma unroll
    for (int m = 0; m < 4; ++m) {
      acc0[m] = f32x4{bb0, bb0, bb0, bb0};
      acc1[m] = f32x4{bb1, bb1, bb1, bb1};
    }
#pragma unroll
    for (int kk = 0; kk < 4; ++kk) {
      const bf16x8 bf0 = *reinterpret_cast<const bf16x8*>(&pack2[((kk * 8 + 2 * w + 0) * 64 + lane) * 4]);
      const bf16x8 bf1 = *reinterpret_cast<const bf16x8*>(&pack2[((kk * 8 + 2 * w + 1) * 64 + lane) * 4]);
#pragma unroll
      for (int m = 0; m < 4; ++m) {
        const bf16x8 a = *reinterpret_cast<const bf16x8*>(&buf[(16 * m + ln15) * 68 + kk * 16 + g * 4]);
        acc0[m] = __builtin_amdgcn_mfma_f32_16x16x32_bf16(a, bf0, acc0[m], 0, 0, 0);
        acc1[m] = __builtin_amdgcn_mfma_f32_16x16x32_bf16(a, bf1, acc1[m], 0, 0, 0);
      }
    }
  }
  {   // segmented pool -> psf
    const int nseg = nseg_s;
    for (int s = 0; s < nseg; ++s) {
      const int r0 = seg_r0[s], r1 = seg_r0[s + 1];
      float v0 = 0.f, v1 = 0.f;
#pragma unroll
      for (int m = 0; m < 4; ++m)
#pragma unroll
        for (int q = 0; q < 4; ++q) {
          const int row = 16 * m + 4 * g + q;
          const bool in = (row >= r0) & (row < r1);
          v0 = fmaxf(v0, in ? fmaxf(acc0[m][q], 0.f) : 0.f);
          v1 = fmaxf(v1, in ? fmaxf(acc1[m][q], 0.f) : 0.f);
        }
      v0 = fmaxf(v0, __shfl_xor(v0, 16, 64)); v0 = fmaxf(v0, __shfl_xor(v0, 32, 64));
      v1 = fmaxf(v1, __shfl_xor(v1, 16, 64)); v1 = fmaxf(v1, __shfl_xor(v1, 32, 64));
      if (lane < 16) {
        const int c = seg_cid[s], j = seg_j[s];
        if (j < SLOTS - 1) {
          psf[((size_t)c * SLOTS + j) * 128 + colA] = v0;
          psf[((size_t)c * SLOTS + j) * 128 + colB] = v1;
        } else {
          atomicMax((int*)&psf[((size_t)c * SLOTS + (SLOTS - 1)) * 128 + colA], __float_as_int(v0));
          atomicMax((int*)&psf[((size_t)c * SLOTS + (SLOTS - 1)) * 128 + colB], __float_as_int(v1));
        }
      }
    }
  }
}

// ---------- global stack: pooled = combine(psf) ; g1 ; g2 ----------
__global__ __launch_bounds__(256) void k_glob(
    const float* __restrict__ psf, const float* __restrict__ G1,
    const float* __restrict__ gb1, const float* __restrict__ G2,
    const float* __restrict__ gb2, float* __restrict__ out)
{
  __shared__ float pooled[128];
  __shared__ float part[256];
  __shared__ float tg[128];
  const int t = threadIdx.x, c = blockIdx.x;
  if (t < 128) {
    const float* p = psf + (size_t)c * SLOTS * 128 + t;
    pooled[t] = fmaxf(fmaxf(p[0], p[128]), p[256]);
  }
  __syncthreads();
  {
    const int col = t & 127, half = t >> 7;
    float a = half ? 0.f : gb1[col];
#pragma unroll 2
    for (int j = 0; j < 16; ++j) {
      const f32x4 pv = *reinterpret_cast<const f32x4*>(&pooled[half * 64 + 4 * j]);
      a = fmaf(pv[0], G1[(half * 64 + 4 * j + 0) * 128 + col], a);
      a = fmaf(pv[1], G1[(half * 64 + 4 * j + 1) * 128 + col], a);
      a = fmaf(pv[2], G1[(half * 64 + 4 * j + 2) * 128 + col], a);
      a = fmaf(pv[3], G1[(half * 64 + 4 * j + 3) * 128 + col], a);
    }
    part[t] = a;
  }
  __syncthreads();
  if (t < 128) tg[t] = fmaxf(part[t] + part[t + 128], 0.f);
  __syncthreads();
  {
    float a = gb2[t];
#pragma unroll 2
    for (int j = 0; j < 32; ++j) {
      const f32x4 tv = *reinterpret_cast<const f32x4*>(&tg[4 * j]);
      a = fmaf(tv[0], G2[(4 * j + 0) * 256 + t], a);
      a = fmaf(tv[1], G2[(4 * j + 1) * 256 + t], a);
      a = fmaf(tv[2], G2[(4 * j + 2) * 256 + t], a);
      a = fmaf(tv[3], G2[(4 * j + 3) * 256 + t], a);
    }
    out[(size_t)c * 256 + t] = fmaxf(a, 0.f);
  }
}

extern "C" void kernel_launch(void* const* d_in, const int* in_sizes, int n_in,
                              void* d_out, int out_size, void* d_ws, size_t ws_size,
                              hipStream_t stream)
{
  (void)in_sizes; (void)n_in; (void)out_size; (void)ws_size;
  const float* pts  = (const float*)d_in[0];
  const float* feat = (const float*)d_in[1];
  const int*   clus = (const int*)  d_in[2];
  const float* eW1  = (const float*)d_in[3];
  const float* eb1  = (const float*)d_in[4];
  const float* eW2  = (const float*)d_in[5];
  const float* eb2  = (const float*)d_in[6];
  const float* W1   = (const float*)d_in[7];
  const float* b1   = (const float*)d_in[8];
  const float* W2   = (const float*)d_in[9];
  const float* b2   = (const float*)d_in[10];
  const float* G1   = (const float*)d_in[11];
  const float* gb1  = (const float*)d_in[12];
  const float* G2   = (const float*)d_in[13];
  const float* gb2  = (const float*)d_in[14];
  float* out = (float*)d_out;

  // ws layout (u32 units):
  //   [0 .. 786432)   : sort phase hist2d(262144)+base2d(262144) ; later pse (4096*3*64 f32)
  //   totals @786432 (4096) | cstart @790528 (4096)
  //   perm @794624 (262144) | scid @1056768 (262144)
  //   packE @1318912 (1024) | pack1 @1319936 (6144) | pack2 @1326080 (8192)
  //   cproj @1334272 (524288, f32)
  //   psf  @1858560 (4096*3*128 = 1572864, f32)      total ~13.1 MB
  unsigned* ws      = (unsigned*)d_ws;
  unsigned* hist2d  = ws;
  unsigned* base2d  = ws + 262144;
  float*    pse     = (float*)ws;
  unsigned* totals  = ws + 786432;
  unsigned* cstart  = ws + 790528;
  unsigned* perm    = ws + 794624;
  unsigned* scid    = ws + 1056768;
  unsigned* packE   = ws + 1318912;
  unsigned* pack1   = ws + 1319936;
  unsigned* pack2   = ws + 1326080;
  float*    cproj   = (float*)(ws + 1334272);
  float*    psf     = (float*)(ws + 1858560);

  k_init   <<<NBLK + 60, 256, 0, stream>>>(clus, hist2d, eW2, W1, W2,
                                           packE, pack1, pack2);
  k_scan_a <<<64, 256, 0, stream>>>(hist2d, base2d, totals, (float4*)psf);
  k_scatter<<<NBLK, 256, 0, stream>>>(clus, base2d, totals, perm, scid, cstart);
  // zero pse AFTER scatter (pse aliases hist2d/base2d)
  hipMemsetAsync((void*)pse, 0, (size_t)786432 * 4, stream);
  k_enc_t  <<<NT, 256, 0, stream>>>(pts, perm, scid, cstart, eW1, eb1, eb2, packE, pse);
  k_cproj2 <<<CC / 2, 256, 0, stream>>>(pse, W1, b1, cproj);
  k_fc_t   <<<NT, 256, 0, stream>>>(pts, feat, perm, scid, cstart, b2, cproj,
                                    pack1, pack2, psf);
  k_glob   <<<CC, 256, 0, stream>>>(psf, G1, gb1, G2, gb2, out);
}